// Round 7
// baseline (377.196 us; speedup 1.0000x reference)
//
#include <hip/hip_runtime.h>
#include <hip/hip_bf16.h>
#include <math.h>

typedef __bf16 bf16;
typedef __bf16 bf16x4 __attribute__((ext_vector_type(4)));
typedef __bf16 bf16x8 __attribute__((ext_vector_type(8)));
typedef float f32x4 __attribute__((ext_vector_type(4)));
typedef unsigned int u32;

#define MFMA_BF16(a, b, c) __builtin_amdgcn_mfma_f32_16x16x32_bf16(a, b, c, 0, 0, 0)
// async global->LDS, 16B per lane; LDS dest = wave-uniform base + lane*16
#define ASYNC16(g, l)                                                                   \
    __builtin_amdgcn_global_load_lds((const __attribute__((address_space(1))) u32*)(g), \
                                     (__attribute__((address_space(3))) u32*)(l), 16, 0, 0)

// ---------------- transpose + cast fp32 -> bf16 (out[c][r] = in[r][c]) ----------------
__global__ __launch_bounds__(256)
void transpose_cast(const float* __restrict__ in, bf16* __restrict__ out, int rows, int cols) {
    __shared__ float tile[32][33];
    const int tx = threadIdx.x, ty = threadIdx.y;
    const int c0 = blockIdx.x * 32, r0 = blockIdx.y * 32;
    #pragma unroll
    for (int j = 0; j < 4; j++)
        tile[ty + j * 8][tx] = in[(size_t)(r0 + ty + j * 8) * cols + c0 + tx];
    __syncthreads();
    #pragma unroll
    for (int j = 0; j < 4; j++)
        out[(size_t)(c0 + ty + j * 8) * rows + r0 + tx] = (bf16)tile[tx][ty + j * 8];
}

// ---------------- transpose V out of qkv: vt[(b*16+h)*64+d][t] = qkv[b][t][2048+h*64+d] ----------------
__global__ __launch_bounds__(256)
void transpose_v(const bf16* __restrict__ qkv, bf16* __restrict__ vt) {
    __shared__ bf16 tile[32][33];
    const int tx = threadIdx.x, ty = threadIdx.y;  // (32,8)
    const int t0 = blockIdx.x * 32;
    const int d0 = blockIdx.y * 32;
    const int bh = blockIdx.z;
    const int b = bh >> 4, h = bh & 15;
    const bf16* src = qkv + (size_t)b * 2048 * 3072 + 2048 + h * 64;
    #pragma unroll
    for (int j = 0; j < 4; j++)
        tile[ty + j * 8][tx] = src[(size_t)(t0 + ty + j * 8) * 3072 + d0 + tx];
    __syncthreads();
    #pragma unroll
    for (int j = 0; j < 4; j++)
        vt[((size_t)bh * 64 + d0 + ty + j * 8) * 2048 + t0 + tx] = tile[tx][ty + j * 8];
}

// ---------------- LayerNorm fp32 -> bf16, D=1024, one block per row ----------------
__global__ __launch_bounds__(256)
void ln_kernel(const float* __restrict__ x, const float* __restrict__ g,
               const float* __restrict__ bb, bf16* __restrict__ out) {
    const int row = blockIdx.x, tid = threadIdx.x;
    const float4 v = reinterpret_cast<const float4*>(x)[(size_t)row * 256 + tid];
    float s = v.x + v.y + v.z + v.w;
    float sq = v.x * v.x + v.y * v.y + v.z * v.z + v.w * v.w;
    #pragma unroll
    for (int o = 32; o > 0; o >>= 1) { s += __shfl_xor(s, o); sq += __shfl_xor(sq, o); }
    __shared__ float ssum[4], ssq[4];
    const int wave = tid >> 6, lane = tid & 63;
    if (lane == 0) { ssum[wave] = s; ssq[wave] = sq; }
    __syncthreads();
    s = ssum[0] + ssum[1] + ssum[2] + ssum[3];
    sq = ssq[0] + ssq[1] + ssq[2] + ssq[3];
    const float mean = s * (1.0f / 1024.0f);
    const float var = sq * (1.0f / 1024.0f) - mean * mean;
    const float rstd = rsqrtf(var + 1e-5f);
    const float4 gv = reinterpret_cast<const float4*>(g)[tid];
    const float4 bv = reinterpret_cast<const float4*>(bb)[tid];
    bf16x4 o;
    o[0] = (bf16)((v.x - mean) * rstd * gv.x + bv.x);
    o[1] = (bf16)((v.y - mean) * rstd * gv.y + bv.y);
    o[2] = (bf16)((v.z - mean) * rstd * gv.z + bv.z);
    o[3] = (bf16)((v.w - mean) * rstd * gv.w + bv.w);
    reinterpret_cast<bf16x4*>(out)[(size_t)row * 256 + tid] = o;
}

// fast exact-enough GELU: v * sigmoid(1.595769122*(v + 0.044715 v^3)); max dev vs erf-gelu ~3e-4
__device__ __forceinline__ float gelu_fast(float v) {
    const float vv = v * v;
    const float u = v * (1.595769122f + 0.0713548162726f * vv);
    const float t = exp2f(u * -1.4426950408889634f);   // e^{-u}
    return v / (1.0f + t);
}

// ---------------- GEMM 256x256 tile, 8-phase schedule (T3+T4+T5), BK=64 ----------------
// launch_bounds (512, 1): the 256^2 schedule needs ~240 regs/thread (128 acc + frags);
// (512,2) capped the unified VGPR/AGPR file at 128/wave and spilled the accumulator
// (R6 counters: VGPR=112, FETCH/WRITE 3-5x compulsory, MfmaUtil 13%).
template <int EPI>
__global__ __launch_bounds__(512, 1)
void gemm256(const bf16* __restrict__ A, const bf16* __restrict__ Bt,
             bf16* __restrict__ outb, int M, int N, int K) {
    __shared__ bf16 As[2][2][2][128][32];   // [dbuf][Mhalf][kslab][row][32k]
    __shared__ bf16 Bs[2][2][2][128][32];   // [dbuf][Nhalf][kslab][row][32k]
    const int tid = threadIdx.x;
    const int wave = tid >> 6, lane = tid & 63;
    const int lm = lane & 15, lq = lane >> 4;
    const int wr = wave >> 2, wc = wave & 3;           // wave tile: (wr*128, wc*64)
    const int bm = blockIdx.y * 256, bn = blockIdx.x * 256;
    const int srow = lane >> 2;                              // staging row 0..15
    const int sg = (((lane & 3) ^ ((lane >> 3) & 3)) * 8);   // swizzled source col (bf16)
    const int pco = (lq ^ ((lm >> 1) & 3)) * 8;              // reader phys col (bf16)

    f32x4 acc[8][4];
    #pragma unroll
    for (int i = 0; i < 8; i++)
        #pragma unroll
        for (int j = 0; j < 4; j++) acc[i][j] = (f32x4){0.f, 0.f, 0.f, 0.f};

    auto stageA = [&](int db, int kt) {
        #pragma unroll
        for (int L = 0; L < 2; L++) {
            const int g = wave * 2 + L, slab = g >> 3, rg = g & 7;
            #pragma unroll
            for (int h = 0; h < 2; h++)
                ASYNC16(A + (size_t)(bm + h * 128 + rg * 16 + srow) * K + kt + slab * 32 + sg,
                        &As[db][h][slab][rg * 16][0]);
        }
    };
    auto stageB = [&](int db, int kt) {
        #pragma unroll
        for (int L = 0; L < 2; L++) {
            const int g = wave * 2 + L, slab = g >> 3, rg = g & 7;
            #pragma unroll
            for (int h = 0; h < 2; h++)
                ASYNC16(Bt + (size_t)(bn + h * 128 + rg * 16 + srow) * K + kt + slab * 32 + sg,
                        &Bs[db][h][slab][rg * 16][0]);
        }
    };
    auto loadA = [&](int db, int mq, bf16x8 (&dst)[4][2]) {
        #pragma unroll
        for (int i = 0; i < 4; i++)
            #pragma unroll
            for (int kk = 0; kk < 2; kk++)
                dst[i][kk] = *reinterpret_cast<const bf16x8*>(
                    &As[db][wr][kk][(mq * 4 + i) * 16 + lm][pco]);
    };
    auto loadB = [&](int db, int bq, bf16x8 (&dst)[2][2]) {
        #pragma unroll
        for (int j = 0; j < 2; j++)
            #pragma unroll
            for (int kk = 0; kk < 2; kk++)
                dst[j][kk] = *reinterpret_cast<const bf16x8*>(
                    &Bs[db][wc >> 1][kk][(wc & 1) * 64 + (bq * 2 + j) * 16 + lm][pco]);
    };
    auto quad = [&](int mq, int bq, bf16x8 (&a)[4][2], bf16x8 (&b)[2][2]) {
        #pragma unroll
        for (int kk = 0; kk < 2; kk++)
            #pragma unroll
            for (int i = 0; i < 4; i++)
                #pragma unroll
                for (int j = 0; j < 2; j++)
                    acc[mq * 4 + i][bq * 2 + j] =
                        MFMA_BF16(a[i][kk], b[j][kk], acc[mq * 4 + i][bq * 2 + j]);
    };

#define PHASE_SYNC()                                         \
    __builtin_amdgcn_s_barrier();                            \
    asm volatile("s_waitcnt lgkmcnt(0)" ::: "memory");       \
    __builtin_amdgcn_sched_barrier(0)

    const int NT = K >> 6;
    stageB(0, 0);  stageA(0, 0);
    stageB(1, 64); stageA(1, 64);
    asm volatile("s_waitcnt vmcnt(8)" ::: "memory");
    __builtin_amdgcn_s_barrier();
    __builtin_amdgcn_sched_barrier(0);

    bf16x8 af[4][2], b0[2][2], b1[2][2];
    for (int t = 0; t < NT; ++t) {
        const int db = t & 1;
        const int kt2 = (t + 2) * 64;
        // ---- p0: quad(m-lo, n-lo) ----
        loadA(db, 0, af);
        loadB(db, 0, b0);
        PHASE_SYNC();
        __builtin_amdgcn_s_setprio(1);
        quad(0, 0, af, b0);
        __builtin_amdgcn_s_setprio(0);
        __builtin_amdgcn_s_barrier();
        // ---- p1: quad(m-lo, n-hi) ----
        loadB(db, 1, b1);
        PHASE_SYNC();
        __builtin_amdgcn_s_setprio(1);
        quad(0, 1, af, b1);
        __builtin_amdgcn_s_setprio(0);
        __builtin_amdgcn_s_barrier();
        // ---- p2: quad(m-hi, n-lo); stage B(t+2) into db (B halves free after p1) ----
        loadA(db, 1, af);
        if (t + 2 < NT) stageB(db, kt2);
        PHASE_SYNC();
        __builtin_amdgcn_s_setprio(1);
        quad(1, 0, af, b0);
        __builtin_amdgcn_s_setprio(0);
        __builtin_amdgcn_s_barrier();
        // ---- p3: quad(m-hi, n-hi); stage A(t+2) into db (A halves free after p2); fence ----
        if (t + 2 < NT) {
            stageA(db, kt2);
            asm volatile("s_waitcnt vmcnt(8)" ::: "memory");   // retire all of tile t+1
        } else if (t + 1 < NT) {
            asm volatile("s_waitcnt vmcnt(0)" ::: "memory");   // final drain before last tile
        }
        __builtin_amdgcn_s_barrier();
        __builtin_amdgcn_sched_barrier(0);
        __builtin_amdgcn_s_setprio(1);
        quad(1, 1, af, b1);
        __builtin_amdgcn_s_setprio(0);
        __builtin_amdgcn_s_barrier();
    }
#undef PHASE_SYNC

    const int r0 = bm + wr * 128, c0 = bn + wc * 64;
    #pragma unroll
    for (int mi = 0; mi < 8; mi++)
        #pragma unroll
        for (int ni = 0; ni < 4; ni++)
            #pragma unroll
            for (int e = 0; e < 4; e++) {
                const int row = r0 + mi * 16 + lq * 4 + e;
                const int col = c0 + ni * 16 + lm;
                const float v = acc[mi][ni][e];
                const size_t idx = (size_t)row * N + col;
                if (EPI == 0) outb[idx] = (bf16)v;
                else          outb[idx] = (bf16)gelu_fast(v);
            }
}

// ---------------- GEMM 256x256 split-K: same 8-phase schedule, atomicAdd fp32 epilogue ----
// For N=1024, K=4096 (fc2): grid (N/256, M/256, 4 K-slices) = 256 blocks = 1/CU.
// launch_bounds (512, 1) — see gemm256 comment (R6: (512,2) spilled the accumulator).
__global__ __launch_bounds__(512, 1)
void gemm256sk(const bf16* __restrict__ A, const bf16* __restrict__ Bt,
               float* __restrict__ outf, int M, int N, int K, int klen) {
    __shared__ bf16 As[2][2][2][128][32];
    __shared__ bf16 Bs[2][2][2][128][32];
    const int tid = threadIdx.x;
    const int wave = tid >> 6, lane = tid & 63;
    const int lm = lane & 15, lq = lane >> 4;
    const int wr = wave >> 2, wc = wave & 3;
    const int bm = blockIdx.y * 256, bn = blockIdx.x * 256;
    const int kbase = blockIdx.z * klen;
    const int srow = lane >> 2;
    const int sg = (((lane & 3) ^ ((lane >> 3) & 3)) * 8);
    const int pco = (lq ^ ((lm >> 1) & 3)) * 8;

    f32x4 acc[8][4];
    #pragma unroll
    for (int i = 0; i < 8; i++)
        #pragma unroll
        for (int j = 0; j < 4; j++) acc[i][j] = (f32x4){0.f, 0.f, 0.f, 0.f};

    auto stageA = [&](int db, int kt) {
        #pragma unroll
        for (int L = 0; L < 2; L++) {
            const int g = wave * 2 + L, slab = g >> 3, rg = g & 7;
            #pragma unroll
            for (int h = 0; h < 2; h++)
                ASYNC16(A + (size_t)(bm + h * 128 + rg * 16 + srow) * K + kbase + kt + slab * 32 + sg,
                        &As[db][h][slab][rg * 16][0]);
        }
    };
    auto stageB = [&](int db, int kt) {
        #pragma unroll
        for (int L = 0; L < 2; L++) {
            const int g = wave * 2 + L, slab = g >> 3, rg = g & 7;
            #pragma unroll
            for (int h = 0; h < 2; h++)
                ASYNC16(Bt + (size_t)(bn + h * 128 + rg * 16 + srow) * K + kbase + kt + slab * 32 + sg,
                        &Bs[db][h][slab][rg * 16][0]);
        }
    };
    auto loadA = [&](int db, int mq, bf16x8 (&dst)[4][2]) {
        #pragma unroll
        for (int i = 0; i < 4; i++)
            #pragma unroll
            for (int kk = 0; kk < 2; kk++)
                dst[i][kk] = *reinterpret_cast<const bf16x8*>(
                    &As[db][wr][kk][(mq * 4 + i) * 16 + lm][pco]);
    };
    auto loadB = [&](int db, int bq, bf16x8 (&dst)[2][2]) {
        #pragma unroll
        for (int j = 0; j < 2; j++)
            #pragma unroll
            for (int kk = 0; kk < 2; kk++)
                dst[j][kk] = *reinterpret_cast<const bf16x8*>(
                    &Bs[db][wc >> 1][kk][(wc & 1) * 64 + (bq * 2 + j) * 16 + lm][pco]);
    };
    auto quad = [&](int mq, int bq, bf16x8 (&a)[4][2], bf16x8 (&b)[2][2]) {
        #pragma unroll
        for (int kk = 0; kk < 2; kk++)
            #pragma unroll
            for (int i = 0; i < 4; i++)
                #pragma unroll
                for (int j = 0; j < 2; j++)
                    acc[mq * 4 + i][bq * 2 + j] =
                        MFMA_BF16(a[i][kk], b[j][kk], acc[mq * 4 + i][bq * 2 + j]);
    };

#define PHASE_SYNC()                                         \
    __builtin_amdgcn_s_barrier();                            \
    asm volatile("s_waitcnt lgkmcnt(0)" ::: "memory");       \
    __builtin_amdgcn_sched_barrier(0)

    const int NT = klen >> 6;
    stageB(0, 0);  stageA(0, 0);
    stageB(1, 64); stageA(1, 64);
    asm volatile("s_waitcnt vmcnt(8)" ::: "memory");
    __builtin_amdgcn_s_barrier();
    __builtin_amdgcn_sched_barrier(0);

    bf16x8 af[4][2], b0[2][2], b1[2][2];
    for (int t = 0; t < NT; ++t) {
        const int db = t & 1;
        const int kt2 = (t + 2) * 64;
        loadA(db, 0, af);
        loadB(db, 0, b0);
        PHASE_SYNC();
        __builtin_amdgcn_s_setprio(1);
        quad(0, 0, af, b0);
        __builtin_amdgcn_s_setprio(0);
        __builtin_amdgcn_s_barrier();
        loadB(db, 1, b1);
        PHASE_SYNC();
        __builtin_amdgcn_s_setprio(1);
        quad(0, 1, af, b1);
        __builtin_amdgcn_s_setprio(0);
        __builtin_amdgcn_s_barrier();
        loadA(db, 1, af);
        if (t + 2 < NT) stageB(db, kt2);
        PHASE_SYNC();
        __builtin_amdgcn_s_setprio(1);
        quad(1, 0, af, b0);
        __builtin_amdgcn_s_setprio(0);
        __builtin_amdgcn_s_barrier();
        if (t + 2 < NT) {
            stageA(db, kt2);
            asm volatile("s_waitcnt vmcnt(8)" ::: "memory");
        } else if (t + 1 < NT) {
            asm volatile("s_waitcnt vmcnt(0)" ::: "memory");
        }
        __builtin_amdgcn_s_barrier();
        __builtin_amdgcn_sched_barrier(0);
        __builtin_amdgcn_s_setprio(1);
        quad(1, 1, af, b1);
        __builtin_amdgcn_s_setprio(0);
        __builtin_amdgcn_s_barrier();
    }
#undef PHASE_SYNC

    const int r0 = bm + wr * 128, c0 = bn + wc * 64;
    #pragma unroll
    for (int mi = 0; mi < 8; mi++)
        #pragma unroll
        for (int ni = 0; ni < 4; ni++)
            #pragma unroll
            for (int e = 0; e < 4; e++) {
                const int row = r0 + mi * 16 + lq * 4 + e;
                const int col = c0 + ni * 16 + lm;
                atomicAdd(&outf[(size_t)row * N + col], acc[mi][ni][e]);
            }
}

// ---------------- GEMM 128x128, 8 waves, BK=64, TRIPLE-buffered, 2 phases/K-tile ----------------
// (kept for proj, K=1024 — small dispatch)
__global__ __launch_bounds__(512, 2)
void gemm128p(const bf16* __restrict__ A, const bf16* __restrict__ Bt,
              const float* __restrict__ resid, float* __restrict__ outf,
              int M, int N, int K) {
    __shared__ bf16 As[3][128][64];
    __shared__ bf16 Bs[3][128][64];
    const int tid = threadIdx.x;
    const int wave = tid >> 6, lane = tid & 63;
    const int lm = lane & 15, lq = lane >> 4;
    const int wm = (wave >> 2) * 64, wn = (wave & 3) * 32;
    const int bm = blockIdx.y * 128, bn = blockIdx.x * 128;
    const int lr8 = lane >> 3;                       // row 0..7 within 8-row chunk
    const int lg  = ((lane & 7) ^ lr8) * 8;          // XOR-swizzled global col group (bf16)
    const int sa  = lm & 7;
    int co[2];
    co[0] = (lq ^ sa) * 8;                           // phys col, kslab 0
    co[1] = ((lq ^ 4) ^ sa) * 8;                     // phys col, kslab 1
    f32x4 acc[4][2];
    #pragma unroll
    for (int i = 0; i < 4; i++)
        #pragma unroll
        for (int j = 0; j < 2; j++) acc[i][j] = (f32x4){0.f, 0.f, 0.f, 0.f};

    auto stageA = [&](int s, int kt) {
        #pragma unroll
        for (int c = 0; c < 2; c++)
            ASYNC16(A + (size_t)(bm + (wave * 2 + c) * 8 + lr8) * K + kt + lg,
                    &As[s][(wave * 2 + c) * 8][0]);
    };
    auto stageB = [&](int s, int kt) {
        #pragma unroll
        for (int c = 0; c < 2; c++)
            ASYNC16(Bt + (size_t)(bn + (wave * 2 + c) * 8 + lr8) * K + kt + lg,
                    &Bs[s][(wave * 2 + c) * 8][0]);
    };

    const int NT = K >> 6;
    stageA(0, 0);  stageB(0, 0);
    stageA(1, 64); stageB(1, 64);
    asm volatile("s_waitcnt vmcnt(4)" ::: "memory");
    __builtin_amdgcn_s_barrier();
    __builtin_amdgcn_sched_barrier(0);

    int s = 0;
    for (int t = 0; t < NT; ++t) {
        const int s2 = (s + 2 >= 3) ? s - 1 : s + 2;   // (t+2) % 3
        const int kt2 = (t + 2) * 64;
        bf16x8 a0[4], b0[2];
        // ---- p0: kslab 0 ----
        #pragma unroll
        for (int mi = 0; mi < 4; mi++)
            a0[mi] = *reinterpret_cast<const bf16x8*>(&As[s][wm + mi * 16 + lm][co[0]]);
        #pragma unroll
        for (int nj = 0; nj < 2; nj++)
            b0[nj] = *reinterpret_cast<const bf16x8*>(&Bs[s][wn + nj * 16 + lm][co[0]]);
        if (t + 2 < NT) stageA(s2, kt2);
        __builtin_amdgcn_s_barrier();
        asm volatile("s_waitcnt lgkmcnt(0)" ::: "memory");
        __builtin_amdgcn_sched_barrier(0);
        __builtin_amdgcn_s_setprio(1);
        #pragma unroll
        for (int mi = 0; mi < 4; mi++)
            #pragma unroll
            for (int nj = 0; nj < 2; nj++)
                acc[mi][nj] = MFMA_BF16(a0[mi], b0[nj], acc[mi][nj]);
        __builtin_amdgcn_s_setprio(0);
        __builtin_amdgcn_s_barrier();
        // ---- p1: kslab 1 ----
        #pragma unroll
        for (int mi = 0; mi < 4; mi++)
            a0[mi] = *reinterpret_cast<const bf16x8*>(&As[s][wm + mi * 16 + lm][co[1]]);
        #pragma unroll
        for (int nj = 0; nj < 2; nj++)
            b0[nj] = *reinterpret_cast<const bf16x8*>(&Bs[s][wn + nj * 16 + lm][co[1]]);
        if (t + 2 < NT) {
            stageB(s2, kt2);
            asm volatile("s_waitcnt vmcnt(4)" ::: "memory");
        } else if (t + 1 < NT) {
            asm volatile("s_waitcnt vmcnt(0)" ::: "memory");
        }
        __builtin_amdgcn_s_barrier();
        asm volatile("s_waitcnt lgkmcnt(0)" ::: "memory");
        __builtin_amdgcn_sched_barrier(0);
        __builtin_amdgcn_s_setprio(1);
        #pragma unroll
        for (int mi = 0; mi < 4; mi++)
            #pragma unroll
            for (int nj = 0; nj < 2; nj++)
                acc[mi][nj] = MFMA_BF16(a0[mi], b0[nj], acc[mi][nj]);
        __builtin_amdgcn_s_setprio(0);
        __builtin_amdgcn_s_barrier();
        s = (s == 2) ? 0 : s + 1;
    }

    const int r0 = bm + wm, c0 = bn + wn;
    #pragma unroll
    for (int i = 0; i < 4; i++)
        #pragma unroll
        for (int j = 0; j < 2; j++)
            #pragma unroll
            for (int e = 0; e < 4; e++) {
                const int row = r0 + i * 16 + lq * 4 + e;
                const int col = c0 + j * 16 + lm;
                const size_t idx = (size_t)row * N + col;
                outf[idx] = resid[idx] + acc[i][j][e];
            }
}

// ---------------- Flash attention, causal, hd=64, T=2048, H=16 ----------------
__global__ __launch_bounds__(256)
void attn_kernel(const bf16* __restrict__ qkv, const bf16* __restrict__ vt,
                 bf16* __restrict__ y) {
    __shared__ bf16 Ks[64][68];        // [key][hd]; stride 34 dw -> 2-way max on b128
    __shared__ bf16 Vt[64][68];        // [hd][key]
    __shared__ bf16 Ps[4][16][68];     // per-wave P tile [qrow][key]
    const int tid = threadIdx.x, wave = tid >> 6, lane = tid & 63;
    const int lm = lane & 15, lq = lane >> 4;
    const int h = blockIdx.y, b = blockIdx.z;
    const size_t base = (size_t)b * 2048 * 3072;
    const bf16* Kbase = qkv + base + 1024 + h * 64;
    const bf16* Vbase = vt + ((size_t)(b * 16 + h) * 64) * 2048;
    const int skey = tid >> 3, sch = (tid & 7) * 8;
    const float k1 = 0.18033688011112042f;   // 0.125 * log2(e)

    bf16x8 ones;
    #pragma unroll
    for (int j = 0; j < 8; j++) ones[j] = (lm == 0) ? (bf16)1.0f : (bf16)0.0f;

    for (int ph = 0; ph < 2; ph++) {
        const int qt = ph ? (int)blockIdx.x : 31 - (int)blockIdx.x;

        const int qrow = qt * 64 + wave * 16 + lm;
        const bf16* qp = qkv + base + (size_t)qrow * 3072 + h * 64 + lq * 8;
        bf16x8 aq0 = *reinterpret_cast<const bf16x8*>(qp);
        bf16x8 aq1 = *reinterpret_cast<const bf16x8*>(qp + 32);
        #pragma unroll
        for (int j = 0; j < 8; j++) {
            aq0[j] = (bf16)((float)aq0[j] * k1);
            aq1[j] = (bf16)((float)aq1[j] * k1);
        }

        f32x4 Oc[4], Ol;
        #pragma unroll
        for (int nt = 0; nt < 4; nt++) Oc[nt] = (f32x4){0.f, 0.f, 0.f, 0.f};
        Ol = (f32x4){0.f, 0.f, 0.f, 0.f};

        bf16x8 pk0, pk1, pv0, pv1;
        {   // prefetch tile 0
            const bf16* kp = Kbase + (size_t)skey * 3072 + sch;
            pk0 = *reinterpret_cast<const bf16x8*>(kp);
            pk1 = *reinterpret_cast<const bf16x8*>(kp + (size_t)32 * 3072);
            const bf16* vp = Vbase + (size_t)skey * 2048 + sch;
            pv0 = *reinterpret_cast<const bf16x8*>(vp);
            pv1 = *reinterpret_cast<const bf16x8*>(vp + (size_t)32 * 2048);
        }

        for (int kt2 = 0; kt2 <= qt; kt2++) {
            __syncthreads();   // previous iteration/phase LDS reads complete
            *reinterpret_cast<bf16x8*>(&Ks[skey][sch])      = pk0;
            *reinterpret_cast<bf16x8*>(&Ks[skey + 32][sch]) = pk1;
            *reinterpret_cast<bf16x8*>(&Vt[skey][sch])      = pv0;
            *reinterpret_cast<bf16x8*>(&Vt[skey + 32][sch]) = pv1;
            __syncthreads();
            if (kt2 < qt) {   // next-tile loads overlap compute
                const bf16* kp = Kbase + (size_t)((kt2 + 1) * 64 + skey) * 3072 + sch;
                pk0 = *reinterpret_cast<const bf16x8*>(kp);
                pk1 = *reinterpret_cast<const bf16x8*>(kp + (size_t)32 * 3072);
                const bf16* vp = Vbase + (size_t)skey * 2048 + (kt2 + 1) * 64 + sch;
                pv0 = *reinterpret_cast<const bf16x8*>(vp);
                pv1 = *reinterpret_cast<const bf16x8*>(vp + (size_t)32 * 2048);
            }

            f32x4 Sc[4];
            #pragma unroll
            for (int nt = 0; nt < 4; nt++) Sc[nt] = (f32x4){0.f, 0.f, 0.f, 0.f};
            #pragma unroll
            for (int nt = 0; nt < 4; nt++) {
                const bf16x8 bk0 = *reinterpret_cast<const bf16x8*>(&Ks[nt * 16 + lm][lq * 8]);
                const bf16x8 bk1 = *reinterpret_cast<const bf16x8*>(&Ks[nt * 16 + lm][32 + lq * 8]);
                Sc[nt] = MFMA_BF16(aq0, bk0, Sc[nt]);
                Sc[nt] = MFMA_BF16(aq1, bk1, Sc[nt]);
            }

            // fixed-shift softmax: p = exp2(score); masked -> 0
            const int qb = wave * 16 + lq * 4;
            #pragma unroll
            for (int e = 0; e < 4; e++) {
                #pragma unroll
                for (int nt = 0; nt < 4; nt++) {
                    float sv = Sc[nt][e];
                    if (kt2 == qt && (nt * 16 + lm) > (qb + e)) sv = -1e30f;
                    Ps[wave][lq * 4 + e][nt * 16 + lm] = (bf16)exp2f(sv);
                }
            }

            const bf16x8 ap0 = *reinterpret_cast<const bf16x8*>(&Ps[wave][lm][lq * 8]);
            const bf16x8 ap1 = *reinterpret_cast<const bf16x8*>(&Ps[wave][lm][32 + lq * 8]);
            Ol = MFMA_BF16(ap0, ones, Ol);      // row-sum l into column 0
            Ol = MFMA_BF16(ap1, ones, Ol);
            #pragma unroll
            for (int nt = 0; nt < 4; nt++) {
                const bf16x8 bv0 = *reinterpret_cast<const bf16x8*>(&Vt[nt * 16 + lm][lq * 8]);
                const bf16x8 bv1 = *reinterpret_cast<const bf16x8*>(&Vt[nt * 16 + lm][32 + lq * 8]);
                Oc[nt] = MFMA_BF16(ap0, bv0, Oc[nt]);
                Oc[nt] = MFMA_BF16(ap1, bv1, Oc[nt]);
            }
        }

        const int qrow0 = qt * 64 + wave * 16 + lq * 4;
        float inv[4];
        #pragma unroll
        for (int e = 0; e < 4; e++) inv[e] = 1.0f / __shfl(Ol[e], lane & 48);
        #pragma unroll
        for (int nt = 0; nt < 4; nt++)
            #pragma unroll
            for (int e = 0; e < 4; e++) {
                const int row = qrow0 + e;
                y[((size_t)b * 2048 + row) * 1024 + h * 64 + nt * 16 + lm] = (bf16)(Oc[nt][e] * inv[e]);
            }
    }
}

// ---------------- launcher ----------------
extern "C" void kernel_launch(void* const* d_in, const int* in_sizes, int n_in,
                              void* d_out, int out_size, void* d_ws, size_t ws_size,
                              hipStream_t stream) {
    const float* x     = (const float*)d_in[0];
    const float* Wqkv  = (const float*)d_in[1];
    const float* Wproj = (const float*)d_in[2];
    const float* Wfc1  = (const float*)d_in[3];
    const float* Wfc2  = (const float*)d_in[4];
    const float* ln1g  = (const float*)d_in[5];
    const float* ln1b  = (const float*)d_in[6];
    const float* ln2g  = (const float*)d_in[7];
    const float* ln2b  = (const float*)d_in[8];
    float* out = (float*)d_out;
    char* ws = (char*)d_ws;

    bf16*  Wqkvt  = (bf16*)(ws);                  //  6 MB [3072][1024]
    bf16*  Wprojt = (bf16*)(ws + 6291456);        //  2 MB [1024][1024]
    bf16*  Wfc1t  = (bf16*)(ws + 8388608);        //  8 MB [4096][1024]
    bf16*  Wfc2t  = (bf16*)(ws + 16777216);       //  8 MB [1024][4096]
    bf16*  hb     = (bf16*)(ws + 25165824);       //  8 MB LN out; dead after qkv GEMM
    bf16*  vt     = (bf16*)(ws + 25165824);       //  8 MB V^T (aliases hb; reused for LN2)
    bf16*  qkv    = (bf16*)(ws + 33554432);       // 24 MB [4096][3072]
    bf16*  yb     = (bf16*)(ws + 58720256);       //  8 MB attn out [4096][1024]
    float* x1     = (float*)(ws + 67108864);      // 16 MB residual fp32
    bf16*  h3     = (bf16*)(ws + 33554432);       // 32 MB gelu out (aliases dead qkv+yb)

    const dim3 tb(32, 8);
    transpose_cast<<<dim3(96, 32), tb, 0, stream>>>(Wqkv, Wqkvt, 1024, 3072);
    transpose_cast<<<dim3(32, 32), tb, 0, stream>>>(Wproj, Wprojt, 1024, 1024);
    transpose_cast<<<dim3(128, 32), tb, 0, stream>>>(Wfc1, Wfc1t, 1024, 4096);
    transpose_cast<<<dim3(32, 128), tb, 0, stream>>>(Wfc2, Wfc2t, 4096, 1024);

    ln_kernel<<<dim3(4096), dim3(256), 0, stream>>>(x, ln1g, ln1b, hb);
    gemm256<0><<<dim3(12, 16), dim3(512), 0, stream>>>(hb, Wqkvt, qkv, 4096, 3072, 1024);
    transpose_v<<<dim3(64, 2, 32), tb, 0, stream>>>(qkv, vt);
    attn_kernel<<<dim3(16, 16, 2), dim3(256), 0, stream>>>(qkv, vt, yb);
    gemm128p<<<dim3(8, 32), dim3(512), 0, stream>>>(yb, Wprojt, x, x1, 4096, 1024, 1024);
    ln_kernel<<<dim3(4096), dim3(256), 0, stream>>>(x1, ln2g, ln2b, hb);
    gemm256<2><<<dim3(16, 16), dim3(512), 0, stream>>>(hb, Wfc1t, h3, 4096, 4096, 1024);
    // fc2: pre-fill out with residual, then 4-way split-K 256^2 GEMM accumulates atomically
    hipMemcpyAsync(out, x1, 16777216, hipMemcpyDeviceToDevice, stream);
    gemm256sk<<<dim3(4, 16, 4), dim3(512), 0, stream>>>(h3, Wfc2t, out, 4096, 1024, 4096, 1024);
}

// Round 8
// 353.990 us; speedup vs baseline: 1.0656x; 1.0656x over previous
//
#include <hip/hip_runtime.h>
#include <hip/hip_bf16.h>
#include <math.h>

typedef __bf16 bf16;
typedef __bf16 bf16x4 __attribute__((ext_vector_type(4)));
typedef __bf16 bf16x8 __attribute__((ext_vector_type(8)));
typedef float f32x4 __attribute__((ext_vector_type(4)));
typedef unsigned int u32;

#define MFMA_BF16(a, b, c) __builtin_amdgcn_mfma_f32_16x16x32_bf16(a, b, c, 0, 0, 0)
// async global->LDS, 16B per lane; LDS dest = wave-uniform base + lane*16
#define ASYNC16(g, l)                                                                   \
    __builtin_amdgcn_global_load_lds((const __attribute__((address_space(1))) u32*)(g), \
                                     (__attribute__((address_space(3))) u32*)(l), 16, 0, 0)

// ---------------- transpose + cast fp32 -> bf16 (out[c][r] = in[r][c]) ----------------
__global__ __launch_bounds__(256)
void transpose_cast(const float* __restrict__ in, bf16* __restrict__ out, int rows, int cols) {
    __shared__ float tile[32][33];
    const int tx = threadIdx.x, ty = threadIdx.y;
    const int c0 = blockIdx.x * 32, r0 = blockIdx.y * 32;
    #pragma unroll
    for (int j = 0; j < 4; j++)
        tile[ty + j * 8][tx] = in[(size_t)(r0 + ty + j * 8) * cols + c0 + tx];
    __syncthreads();
    #pragma unroll
    for (int j = 0; j < 4; j++)
        out[(size_t)(c0 + ty + j * 8) * rows + r0 + tx] = (bf16)tile[tx][ty + j * 8];
}

// ---------------- transpose V out of qkv: vt[(b*16+h)*64+d][t] = qkv[b][t][2048+h*64+d] ----------------
__global__ __launch_bounds__(256)
void transpose_v(const bf16* __restrict__ qkv, bf16* __restrict__ vt) {
    __shared__ bf16 tile[32][33];
    const int tx = threadIdx.x, ty = threadIdx.y;  // (32,8)
    const int t0 = blockIdx.x * 32;
    const int d0 = blockIdx.y * 32;
    const int bh = blockIdx.z;
    const int b = bh >> 4, h = bh & 15;
    const bf16* src = qkv + (size_t)b * 2048 * 3072 + 2048 + h * 64;
    #pragma unroll
    for (int j = 0; j < 4; j++)
        tile[ty + j * 8][tx] = src[(size_t)(t0 + ty + j * 8) * 3072 + d0 + tx];
    __syncthreads();
    #pragma unroll
    for (int j = 0; j < 4; j++)
        vt[((size_t)bh * 64 + d0 + ty + j * 8) * 2048 + t0 + tx] = tile[tx][ty + j * 8];
}

// ---------------- LayerNorm fp32 -> bf16, D=1024, one block per row ----------------
__global__ __launch_bounds__(256)
void ln_kernel(const float* __restrict__ x, const float* __restrict__ g,
               const float* __restrict__ bb, bf16* __restrict__ out) {
    const int row = blockIdx.x, tid = threadIdx.x;
    const float4 v = reinterpret_cast<const float4*>(x)[(size_t)row * 256 + tid];
    float s = v.x + v.y + v.z + v.w;
    float sq = v.x * v.x + v.y * v.y + v.z * v.z + v.w * v.w;
    #pragma unroll
    for (int o = 32; o > 0; o >>= 1) { s += __shfl_xor(s, o); sq += __shfl_xor(sq, o); }
    __shared__ float ssum[4], ssq[4];
    const int wave = tid >> 6, lane = tid & 63;
    if (lane == 0) { ssum[wave] = s; ssq[wave] = sq; }
    __syncthreads();
    s = ssum[0] + ssum[1] + ssum[2] + ssum[3];
    sq = ssq[0] + ssq[1] + ssq[2] + ssq[3];
    const float mean = s * (1.0f / 1024.0f);
    const float var = sq * (1.0f / 1024.0f) - mean * mean;
    const float rstd = rsqrtf(var + 1e-5f);
    const float4 gv = reinterpret_cast<const float4*>(g)[tid];
    const float4 bv = reinterpret_cast<const float4*>(bb)[tid];
    bf16x4 o;
    o[0] = (bf16)((v.x - mean) * rstd * gv.x + bv.x);
    o[1] = (bf16)((v.y - mean) * rstd * gv.y + bv.y);
    o[2] = (bf16)((v.z - mean) * rstd * gv.z + bv.z);
    o[3] = (bf16)((v.w - mean) * rstd * gv.w + bv.w);
    reinterpret_cast<bf16x4*>(out)[(size_t)row * 256 + tid] = o;
}

// fast exact-enough GELU: v * sigmoid(1.595769122*(v + 0.044715 v^3)); max dev vs erf-gelu ~3e-4
__device__ __forceinline__ float gelu_fast(float v) {
    const float vv = v * v;
    const float u = v * (1.595769122f + 0.0713548162726f * vv);
    const float t = exp2f(u * -1.4426950408889634f);   // e^{-u}
    return v / (1.0f + t);
}

// ---------------- GEMM 256x256 tile, 8-phase schedule (unchanged — control for qkv/fc1) ----
template <int EPI>
__global__ __launch_bounds__(512, 1)
void gemm256(const bf16* __restrict__ A, const bf16* __restrict__ Bt,
             bf16* __restrict__ outb, int M, int N, int K) {
    __shared__ bf16 As[2][2][2][128][32];   // [dbuf][Mhalf][kslab][row][32k]
    __shared__ bf16 Bs[2][2][2][128][32];   // [dbuf][Nhalf][kslab][row][32k]
    const int tid = threadIdx.x;
    const int wave = tid >> 6, lane = tid & 63;
    const int lm = lane & 15, lq = lane >> 4;
    const int wr = wave >> 2, wc = wave & 3;           // wave tile: (wr*128, wc*64)
    const int bm = blockIdx.y * 256, bn = blockIdx.x * 256;
    const int srow = lane >> 2;                              // staging row 0..15
    const int sg = (((lane & 3) ^ ((lane >> 3) & 3)) * 8);   // swizzled source col (bf16)
    const int pco = (lq ^ ((lm >> 1) & 3)) * 8;              // reader phys col (bf16)

    f32x4 acc[8][4];
    #pragma unroll
    for (int i = 0; i < 8; i++)
        #pragma unroll
        for (int j = 0; j < 4; j++) acc[i][j] = (f32x4){0.f, 0.f, 0.f, 0.f};

    auto stageA = [&](int db, int kt) {
        #pragma unroll
        for (int L = 0; L < 2; L++) {
            const int g = wave * 2 + L, slab = g >> 3, rg = g & 7;
            #pragma unroll
            for (int h = 0; h < 2; h++)
                ASYNC16(A + (size_t)(bm + h * 128 + rg * 16 + srow) * K + kt + slab * 32 + sg,
                        &As[db][h][slab][rg * 16][0]);
        }
    };
    auto stageB = [&](int db, int kt) {
        #pragma unroll
        for (int L = 0; L < 2; L++) {
            const int g = wave * 2 + L, slab = g >> 3, rg = g & 7;
            #pragma unroll
            for (int h = 0; h < 2; h++)
                ASYNC16(Bt + (size_t)(bn + h * 128 + rg * 16 + srow) * K + kt + slab * 32 + sg,
                        &Bs[db][h][slab][rg * 16][0]);
        }
    };
    auto loadA = [&](int db, int mq, bf16x8 (&dst)[4][2]) {
        #pragma unroll
        for (int i = 0; i < 4; i++)
            #pragma unroll
            for (int kk = 0; kk < 2; kk++)
                dst[i][kk] = *reinterpret_cast<const bf16x8*>(
                    &As[db][wr][kk][(mq * 4 + i) * 16 + lm][pco]);
    };
    auto loadB = [&](int db, int bq, bf16x8 (&dst)[2][2]) {
        #pragma unroll
        for (int j = 0; j < 2; j++)
            #pragma unroll
            for (int kk = 0; kk < 2; kk++)
                dst[j][kk] = *reinterpret_cast<const bf16x8*>(
                    &Bs[db][wc >> 1][kk][(wc & 1) * 64 + (bq * 2 + j) * 16 + lm][pco]);
    };
    auto quad = [&](int mq, int bq, bf16x8 (&a)[4][2], bf16x8 (&b)[2][2]) {
        #pragma unroll
        for (int kk = 0; kk < 2; kk++)
            #pragma unroll
            for (int i = 0; i < 4; i++)
                #pragma unroll
                for (int j = 0; j < 2; j++)
                    acc[mq * 4 + i][bq * 2 + j] =
                        MFMA_BF16(a[i][kk], b[j][kk], acc[mq * 4 + i][bq * 2 + j]);
    };

#define PHASE_SYNC()                                         \
    __builtin_amdgcn_s_barrier();                            \
    asm volatile("s_waitcnt lgkmcnt(0)" ::: "memory");       \
    __builtin_amdgcn_sched_barrier(0)

    const int NT = K >> 6;
    stageB(0, 0);  stageA(0, 0);
    stageB(1, 64); stageA(1, 64);
    asm volatile("s_waitcnt vmcnt(8)" ::: "memory");
    __builtin_amdgcn_s_barrier();
    __builtin_amdgcn_sched_barrier(0);

    bf16x8 af[4][2], b0[2][2], b1[2][2];
    for (int t = 0; t < NT; ++t) {
        const int db = t & 1;
        const int kt2 = (t + 2) * 64;
        // ---- p0: quad(m-lo, n-lo) ----
        loadA(db, 0, af);
        loadB(db, 0, b0);
        PHASE_SYNC();
        __builtin_amdgcn_s_setprio(1);
        quad(0, 0, af, b0);
        __builtin_amdgcn_s_setprio(0);
        __builtin_amdgcn_s_barrier();
        // ---- p1: quad(m-lo, n-hi) ----
        loadB(db, 1, b1);
        PHASE_SYNC();
        __builtin_amdgcn_s_setprio(1);
        quad(0, 1, af, b1);
        __builtin_amdgcn_s_setprio(0);
        __builtin_amdgcn_s_barrier();
        // ---- p2: quad(m-hi, n-lo); stage B(t+2) into db (B halves free after p1) ----
        loadA(db, 1, af);
        if (t + 2 < NT) stageB(db, kt2);
        PHASE_SYNC();
        __builtin_amdgcn_s_setprio(1);
        quad(1, 0, af, b0);
        __builtin_amdgcn_s_setprio(0);
        __builtin_amdgcn_s_barrier();
        // ---- p3: quad(m-hi, n-hi); stage A(t+2) into db (A halves free after p2); fence ----
        if (t + 2 < NT) {
            stageA(db, kt2);
            asm volatile("s_waitcnt vmcnt(8)" ::: "memory");   // retire all of tile t+1
        } else if (t + 1 < NT) {
            asm volatile("s_waitcnt vmcnt(0)" ::: "memory");   // final drain before last tile
        }
        __builtin_amdgcn_s_barrier();
        __builtin_amdgcn_sched_barrier(0);
        __builtin_amdgcn_s_setprio(1);
        quad(1, 1, af, b1);
        __builtin_amdgcn_s_setprio(0);
        __builtin_amdgcn_s_barrier();
    }
#undef PHASE_SYNC

    const int r0 = bm + wr * 128, c0 = bn + wc * 64;
    #pragma unroll
    for (int mi = 0; mi < 8; mi++)
        #pragma unroll
        for (int ni = 0; ni < 4; ni++)
            #pragma unroll
            for (int e = 0; e < 4; e++) {
                const int row = r0 + mi * 16 + lq * 4 + e;
                const int col = c0 + ni * 16 + lm;
                const float v = acc[mi][ni][e];
                const size_t idx = (size_t)row * N + col;
                if (EPI == 0) outb[idx] = (bf16)v;
                else          outb[idx] = (bf16)gelu_fast(v);
            }
}

// ---------------- GEMM 128x128, 4 waves x (64x64 tile), BK=64, double-buffered ----------------
// m97-class geometry: per wave 32 MFMA : 16 ds_read_b128 per K-tile (2x the MFMA/read ratio of
// the 64x32-tile gemm128p, whose ~33% LDS-read ceiling showed as MfmaUtil 22%).
// 64 KB LDS -> 2 blocks/CU: cross-block TLP hides the per-iter vmcnt drain (m97's regime).
// Proven zero-conflict 8-wide XOR layout (64B rows): phys group = logical ^ (row&7).
// Bijective XCD swizzle (nwg%8==0): XCD x gets 4 contiguous A-row-panels (R4: FETCH 143->57MB).
// Epilogue: outf = resid + acc (fp32). Used for proj and fc2 (both N=1024, grid (8,32)=256).
__global__ __launch_bounds__(256)
void gemm128w(const bf16* __restrict__ A, const bf16* __restrict__ Bt,
              const float* __restrict__ resid, float* __restrict__ outf,
              int M, int N, int K) {
    __shared__ bf16 As[2][128][64];
    __shared__ bf16 Bs[2][128][64];
    const int tid = threadIdx.x;
    const int wave = tid >> 6, lane = tid & 63;
    const int lm = lane & 15, lq = lane >> 4;
    const int wm = (wave >> 1) * 64, wn = (wave & 1) * 64;
    // XCD-aware bijective swizzle of the linear workgroup id
    const int nwg = gridDim.x * gridDim.y;
    const int orig = blockIdx.x + gridDim.x * blockIdx.y;
    const int cpx = nwg >> 3;
    const int swz = (orig & 7) * cpx + (orig >> 3);
    const int bx = swz % gridDim.x, by = swz / gridDim.x;
    const int bm = by * 128, bn = bx * 128;
    const int lr8 = lane >> 3;                       // row 0..7 within 8-row cluster
    const int lg  = ((lane & 7) ^ lr8) * 8;          // XOR-swizzled global col group (bf16)
    const int sa  = lm & 7;
    int co[2];
    co[0] = (lq ^ sa) * 8;                           // phys col, kslab 0
    co[1] = ((lq ^ 4) ^ sa) * 8;                     // phys col, kslab 1
    f32x4 acc[4][4];
    #pragma unroll
    for (int i = 0; i < 4; i++)
        #pragma unroll
        for (int j = 0; j < 4; j++) acc[i][j] = (f32x4){0.f, 0.f, 0.f, 0.f};

    // 4 waves x 32 rows each per matrix; 8 ASYNC16 per wave per K-tile
    auto stage = [&](int bb, int kt) {
        #pragma unroll
        for (int s = 0; s < 4; s++)
            ASYNC16(A + (size_t)(bm + wave * 32 + s * 8 + lr8) * K + kt + lg,
                    &As[bb][wave * 32 + s * 8][0]);
        #pragma unroll
        for (int s = 0; s < 4; s++)
            ASYNC16(Bt + (size_t)(bn + wave * 32 + s * 8 + lr8) * K + kt + lg,
                    &Bs[bb][wave * 32 + s * 8][0]);
    };

    stage(0, 0);
    int cur = 0;
    for (int kt = 0; kt < K; kt += 64) {
        __syncthreads();
        if (kt + 64 < K) stage(cur ^ 1, kt + 64);
        bf16x8 af[2][4], bfr[2][4];
        #pragma unroll
        for (int kk = 0; kk < 2; kk++) {
            #pragma unroll
            for (int i = 0; i < 4; i++)
                af[kk][i] = *reinterpret_cast<const bf16x8*>(&As[cur][wm + i * 16 + lm][co[kk]]);
            #pragma unroll
            for (int j = 0; j < 4; j++)
                bfr[kk][j] = *reinterpret_cast<const bf16x8*>(&Bs[cur][wn + j * 16 + lm][co[kk]]);
        }
        #pragma unroll
        for (int kk = 0; kk < 2; kk++)
            #pragma unroll
            for (int i = 0; i < 4; i++)
                #pragma unroll
                for (int j = 0; j < 4; j++)
                    acc[i][j] = MFMA_BF16(af[kk][i], bfr[kk][j], acc[i][j]);
        cur ^= 1;
    }

    const int r0 = bm + wm, c0 = bn + wn;
    #pragma unroll
    for (int i = 0; i < 4; i++)
        #pragma unroll
        for (int j = 0; j < 4; j++)
            #pragma unroll
            for (int e = 0; e < 4; e++) {
                const int row = r0 + i * 16 + lq * 4 + e;
                const int col = c0 + j * 16 + lm;
                const size_t idx = (size_t)row * N + col;
                outf[idx] = resid[idx] + acc[i][j][e];
            }
}

// ---------------- Flash attention, causal, hd=64, T=2048, H=16 ----------------
__global__ __launch_bounds__(256)
void attn_kernel(const bf16* __restrict__ qkv, const bf16* __restrict__ vt,
                 bf16* __restrict__ y) {
    __shared__ bf16 Ks[64][68];        // [key][hd]; stride 34 dw -> 2-way max on b128
    __shared__ bf16 Vt[64][68];        // [hd][key]
    __shared__ bf16 Ps[4][16][68];     // per-wave P tile [qrow][key]
    const int tid = threadIdx.x, wave = tid >> 6, lane = tid & 63;
    const int lm = lane & 15, lq = lane >> 4;
    const int h = blockIdx.y, b = blockIdx.z;
    const size_t base = (size_t)b * 2048 * 3072;
    const bf16* Kbase = qkv + base + 1024 + h * 64;
    const bf16* Vbase = vt + ((size_t)(b * 16 + h) * 64) * 2048;
    const int skey = tid >> 3, sch = (tid & 7) * 8;
    const float k1 = 0.18033688011112042f;   // 0.125 * log2(e)

    bf16x8 ones;
    #pragma unroll
    for (int j = 0; j < 8; j++) ones[j] = (lm == 0) ? (bf16)1.0f : (bf16)0.0f;

    for (int ph = 0; ph < 2; ph++) {
        const int qt = ph ? (int)blockIdx.x : 31 - (int)blockIdx.x;

        const int qrow = qt * 64 + wave * 16 + lm;
        const bf16* qp = qkv + base + (size_t)qrow * 3072 + h * 64 + lq * 8;
        bf16x8 aq0 = *reinterpret_cast<const bf16x8*>(qp);
        bf16x8 aq1 = *reinterpret_cast<const bf16x8*>(qp + 32);
        #pragma unroll
        for (int j = 0; j < 8; j++) {
            aq0[j] = (bf16)((float)aq0[j] * k1);
            aq1[j] = (bf16)((float)aq1[j] * k1);
        }

        f32x4 Oc[4], Ol;
        #pragma unroll
        for (int nt = 0; nt < 4; nt++) Oc[nt] = (f32x4){0.f, 0.f, 0.f, 0.f};
        Ol = (f32x4){0.f, 0.f, 0.f, 0.f};

        bf16x8 pk0, pk1, pv0, pv1;
        {   // prefetch tile 0
            const bf16* kp = Kbase + (size_t)skey * 3072 + sch;
            pk0 = *reinterpret_cast<const bf16x8*>(kp);
            pk1 = *reinterpret_cast<const bf16x8*>(kp + (size_t)32 * 3072);
            const bf16* vp = Vbase + (size_t)skey * 2048 + sch;
            pv0 = *reinterpret_cast<const bf16x8*>(vp);
            pv1 = *reinterpret_cast<const bf16x8*>(vp + (size_t)32 * 2048);
        }

        for (int kt2 = 0; kt2 <= qt; kt2++) {
            __syncthreads();   // previous iteration/phase LDS reads complete
            *reinterpret_cast<bf16x8*>(&Ks[skey][sch])      = pk0;
            *reinterpret_cast<bf16x8*>(&Ks[skey + 32][sch]) = pk1;
            *reinterpret_cast<bf16x8*>(&Vt[skey][sch])      = pv0;
            *reinterpret_cast<bf16x8*>(&Vt[skey + 32][sch]) = pv1;
            __syncthreads();
            if (kt2 < qt) {   // next-tile loads overlap compute
                const bf16* kp = Kbase + (size_t)((kt2 + 1) * 64 + skey) * 3072 + sch;
                pk0 = *reinterpret_cast<const bf16x8*>(kp);
                pk1 = *reinterpret_cast<const bf16x8*>(kp + (size_t)32 * 3072);
                const bf16* vp = Vbase + (size_t)skey * 2048 + (kt2 + 1) * 64 + sch;
                pv0 = *reinterpret_cast<const bf16x8*>(vp);
                pv1 = *reinterpret_cast<const bf16x8*>(vp + (size_t)32 * 2048);
            }

            f32x4 Sc[4];
            #pragma unroll
            for (int nt = 0; nt < 4; nt++) Sc[nt] = (f32x4){0.f, 0.f, 0.f, 0.f};
            #pragma unroll
            for (int nt = 0; nt < 4; nt++) {
                const bf16x8 bk0 = *reinterpret_cast<const bf16x8*>(&Ks[nt * 16 + lm][lq * 8]);
                const bf16x8 bk1 = *reinterpret_cast<const bf16x8*>(&Ks[nt * 16 + lm][32 + lq * 8]);
                Sc[nt] = MFMA_BF16(aq0, bk0, Sc[nt]);
                Sc[nt] = MFMA_BF16(aq1, bk1, Sc[nt]);
            }

            // fixed-shift softmax: p = exp2(score); masked -> 0
            const int qb = wave * 16 + lq * 4;
            #pragma unroll
            for (int e = 0; e < 4; e++) {
                #pragma unroll
                for (int nt = 0; nt < 4; nt++) {
                    float sv = Sc[nt][e];
                    if (kt2 == qt && (nt * 16 + lm) > (qb + e)) sv = -1e30f;
                    Ps[wave][lq * 4 + e][nt * 16 + lm] = (bf16)exp2f(sv);
                }
            }

            const bf16x8 ap0 = *reinterpret_cast<const bf16x8*>(&Ps[wave][lm][lq * 8]);
            const bf16x8 ap1 = *reinterpret_cast<const bf16x8*>(&Ps[wave][lm][32 + lq * 8]);
            Ol = MFMA_BF16(ap0, ones, Ol);      // row-sum l into column 0
            Ol = MFMA_BF16(ap1, ones, Ol);
            #pragma unroll
            for (int nt = 0; nt < 4; nt++) {
                const bf16x8 bv0 = *reinterpret_cast<const bf16x8*>(&Vt[nt * 16 + lm][lq * 8]);
                const bf16x8 bv1 = *reinterpret_cast<const bf16x8*>(&Vt[nt * 16 + lm][32 + lq * 8]);
                Oc[nt] = MFMA_BF16(ap0, bv0, Oc[nt]);
                Oc[nt] = MFMA_BF16(ap1, bv1, Oc[nt]);
            }
        }

        const int qrow0 = qt * 64 + wave * 16 + lq * 4;
        float inv[4];
        #pragma unroll
        for (int e = 0; e < 4; e++) inv[e] = 1.0f / __shfl(Ol[e], lane & 48);
        #pragma unroll
        for (int nt = 0; nt < 4; nt++)
            #pragma unroll
            for (int e = 0; e < 4; e++) {
                const int row = qrow0 + e;
                y[((size_t)b * 2048 + row) * 1024 + h * 64 + nt * 16 + lm] = (bf16)(Oc[nt][e] * inv[e]);
            }
    }
}

// ---------------- launcher ----------------
extern "C" void kernel_launch(void* const* d_in, const int* in_sizes, int n_in,
                              void* d_out, int out_size, void* d_ws, size_t ws_size,
                              hipStream_t stream) {
    const float* x     = (const float*)d_in[0];
    const float* Wqkv  = (const float*)d_in[1];
    const float* Wproj = (const float*)d_in[2];
    const float* Wfc1  = (const float*)d_in[3];
    const float* Wfc2  = (const float*)d_in[4];
    const float* ln1g  = (const float*)d_in[5];
    const float* ln1b  = (const float*)d_in[6];
    const float* ln2g  = (const float*)d_in[7];
    const float* ln2b  = (const float*)d_in[8];
    float* out = (float*)d_out;
    char* ws = (char*)d_ws;

    bf16*  Wqkvt  = (bf16*)(ws);                  //  6 MB [3072][1024]
    bf16*  Wprojt = (bf16*)(ws + 6291456);        //  2 MB [1024][1024]
    bf16*  Wfc1t  = (bf16*)(ws + 8388608);        //  8 MB [4096][1024]
    bf16*  Wfc2t  = (bf16*)(ws + 16777216);       //  8 MB [1024][4096]
    bf16*  hb     = (bf16*)(ws + 25165824);       //  8 MB LN out; dead after qkv GEMM
    bf16*  vt     = (bf16*)(ws + 25165824);       //  8 MB V^T (aliases hb; reused for LN2)
    bf16*  qkv    = (bf16*)(ws + 33554432);       // 24 MB [4096][3072]
    bf16*  yb     = (bf16*)(ws + 58720256);       //  8 MB attn out [4096][1024]
    float* x1     = (float*)(ws + 67108864);      // 16 MB residual fp32
    bf16*  h3     = (bf16*)(ws + 33554432);       // 32 MB gelu out (aliases dead qkv+yb)

    const dim3 tb(32, 8);
    transpose_cast<<<dim3(96, 32), tb, 0, stream>>>(Wqkv, Wqkvt, 1024, 3072);
    transpose_cast<<<dim3(32, 32), tb, 0, stream>>>(Wproj, Wprojt, 1024, 1024);
    transpose_cast<<<dim3(128, 32), tb, 0, stream>>>(Wfc1, Wfc1t, 1024, 4096);
    transpose_cast<<<dim3(32, 128), tb, 0, stream>>>(Wfc2, Wfc2t, 4096, 1024);

    ln_kernel<<<dim3(4096), dim3(256), 0, stream>>>(x, ln1g, ln1b, hb);
    gemm256<0><<<dim3(12, 16), dim3(512), 0, stream>>>(hb, Wqkvt, qkv, 4096, 3072, 1024);
    transpose_v<<<dim3(64, 2, 32), tb, 0, stream>>>(qkv, vt);
    attn_kernel<<<dim3(16, 16, 2), dim3(256), 0, stream>>>(qkv, vt, yb);
    gemm128w<<<dim3(8, 32), dim3(256), 0, stream>>>(yb, Wprojt, x, x1, 4096, 1024, 1024);
    ln_kernel<<<dim3(4096), dim3(256), 0, stream>>>(x1, ln2g, ln2b, hb);
    gemm256<2><<<dim3(16, 16), dim3(512), 0, stream>>>(hb, Wfc1t, h3, 4096, 4096, 1024);
    gemm128w<<<dim3(8, 32), dim3(256), 0, stream>>>(h3, Wfc2t, x1, out, 4096, 1024, 4096);
}

// Round 9
// 336.272 us; speedup vs baseline: 1.1217x; 1.0527x over previous
//
#include <hip/hip_runtime.h>
#include <hip/hip_bf16.h>
#include <math.h>

typedef __bf16 bf16;
typedef __bf16 bf16x4 __attribute__((ext_vector_type(4)));
typedef __bf16 bf16x8 __attribute__((ext_vector_type(8)));
typedef float f32x4 __attribute__((ext_vector_type(4)));
typedef unsigned int u32;

#define MFMA_BF16(a, b, c) __builtin_amdgcn_mfma_f32_16x16x32_bf16(a, b, c, 0, 0, 0)
// async global->LDS, 16B per lane; LDS dest = wave-uniform base + lane*16
#define ASYNC16(g, l)                                                                   \
    __builtin_amdgcn_global_load_lds((const __attribute__((address_space(1))) u32*)(g), \
                                     (__attribute__((address_space(3))) u32*)(l), 16, 0, 0)

// ---------------- transpose + cast fp32 -> bf16 (out[c][r] = in[r][c]) ----------------
__global__ __launch_bounds__(256)
void transpose_cast(const float* __restrict__ in, bf16* __restrict__ out, int rows, int cols) {
    __shared__ float tile[32][33];
    const int tx = threadIdx.x, ty = threadIdx.y;
    const int c0 = blockIdx.x * 32, r0 = blockIdx.y * 32;
    #pragma unroll
    for (int j = 0; j < 4; j++)
        tile[ty + j * 8][tx] = in[(size_t)(r0 + ty + j * 8) * cols + c0 + tx];
    __syncthreads();
    #pragma unroll
    for (int j = 0; j < 4; j++)
        out[(size_t)(c0 + ty + j * 8) * rows + r0 + tx] = (bf16)tile[tx][ty + j * 8];
}

// ---------------- transpose V out of qkv: vt[(b*16+h)*64+d][t] = qkv[b][t][2048+h*64+d] ----------------
__global__ __launch_bounds__(256)
void transpose_v(const bf16* __restrict__ qkv, bf16* __restrict__ vt) {
    __shared__ bf16 tile[32][33];
    const int tx = threadIdx.x, ty = threadIdx.y;  // (32,8)
    const int t0 = blockIdx.x * 32;
    const int d0 = blockIdx.y * 32;
    const int bh = blockIdx.z;
    const int b = bh >> 4, h = bh & 15;
    const bf16* src = qkv + (size_t)b * 2048 * 3072 + 2048 + h * 64;
    #pragma unroll
    for (int j = 0; j < 4; j++)
        tile[ty + j * 8][tx] = src[(size_t)(t0 + ty + j * 8) * 3072 + d0 + tx];
    __syncthreads();
    #pragma unroll
    for (int j = 0; j < 4; j++)
        vt[((size_t)bh * 64 + d0 + ty + j * 8) * 2048 + t0 + tx] = tile[tx][ty + j * 8];
}

// ---------------- LayerNorm fp32 -> bf16, D=1024, one block per row ----------------
__global__ __launch_bounds__(256)
void ln_kernel(const float* __restrict__ x, const float* __restrict__ g,
               const float* __restrict__ bb, bf16* __restrict__ out) {
    const int row = blockIdx.x, tid = threadIdx.x;
    const float4 v = reinterpret_cast<const float4*>(x)[(size_t)row * 256 + tid];
    float s = v.x + v.y + v.z + v.w;
    float sq = v.x * v.x + v.y * v.y + v.z * v.z + v.w * v.w;
    #pragma unroll
    for (int o = 32; o > 0; o >>= 1) { s += __shfl_xor(s, o); sq += __shfl_xor(sq, o); }
    __shared__ float ssum[4], ssq[4];
    const int wave = tid >> 6, lane = tid & 63;
    if (lane == 0) { ssum[wave] = s; ssq[wave] = sq; }
    __syncthreads();
    s = ssum[0] + ssum[1] + ssum[2] + ssum[3];
    sq = ssq[0] + ssq[1] + ssq[2] + ssq[3];
    const float mean = s * (1.0f / 1024.0f);
    const float var = sq * (1.0f / 1024.0f) - mean * mean;
    const float rstd = rsqrtf(var + 1e-5f);
    const float4 gv = reinterpret_cast<const float4*>(g)[tid];
    const float4 bv = reinterpret_cast<const float4*>(bb)[tid];
    bf16x4 o;
    o[0] = (bf16)((v.x - mean) * rstd * gv.x + bv.x);
    o[1] = (bf16)((v.y - mean) * rstd * gv.y + bv.y);
    o[2] = (bf16)((v.z - mean) * rstd * gv.z + bv.z);
    o[3] = (bf16)((v.w - mean) * rstd * gv.w + bv.w);
    reinterpret_cast<bf16x4*>(out)[(size_t)row * 256 + tid] = o;
}

// fast exact-enough GELU: v * sigmoid(1.595769122*(v + 0.044715 v^3)); max dev vs erf-gelu ~3e-4
__device__ __forceinline__ float gelu_fast(float v) {
    const float vv = v * v;
    const float u = v * (1.595769122f + 0.0713548162726f * vv);
    const float t = exp2f(u * -1.4426950408889634f);   // e^{-u}
    return v / (1.0f + t);
}

// ---------------- GEMM 256x256 tile, 8-phase schedule (unchanged — qkv/fc1) ----
template <int EPI>
__global__ __launch_bounds__(512, 1)
void gemm256(const bf16* __restrict__ A, const bf16* __restrict__ Bt,
             bf16* __restrict__ outb, int M, int N, int K) {
    __shared__ bf16 As[2][2][2][128][32];   // [dbuf][Mhalf][kslab][row][32k]
    __shared__ bf16 Bs[2][2][2][128][32];   // [dbuf][Nhalf][kslab][row][32k]
    const int tid = threadIdx.x;
    const int wave = tid >> 6, lane = tid & 63;
    const int lm = lane & 15, lq = lane >> 4;
    const int wr = wave >> 2, wc = wave & 3;           // wave tile: (wr*128, wc*64)
    const int bm = blockIdx.y * 256, bn = blockIdx.x * 256;
    const int srow = lane >> 2;                              // staging row 0..15
    const int sg = (((lane & 3) ^ ((lane >> 3) & 3)) * 8);   // swizzled source col (bf16)
    const int pco = (lq ^ ((lm >> 1) & 3)) * 8;              // reader phys col (bf16)

    f32x4 acc[8][4];
    #pragma unroll
    for (int i = 0; i < 8; i++)
        #pragma unroll
        for (int j = 0; j < 4; j++) acc[i][j] = (f32x4){0.f, 0.f, 0.f, 0.f};

    auto stageA = [&](int db, int kt) {
        #pragma unroll
        for (int L = 0; L < 2; L++) {
            const int g = wave * 2 + L, slab = g >> 3, rg = g & 7;
            #pragma unroll
            for (int h = 0; h < 2; h++)
                ASYNC16(A + (size_t)(bm + h * 128 + rg * 16 + srow) * K + kt + slab * 32 + sg,
                        &As[db][h][slab][rg * 16][0]);
        }
    };
    auto stageB = [&](int db, int kt) {
        #pragma unroll
        for (int L = 0; L < 2; L++) {
            const int g = wave * 2 + L, slab = g >> 3, rg = g & 7;
            #pragma unroll
            for (int h = 0; h < 2; h++)
                ASYNC16(Bt + (size_t)(bn + h * 128 + rg * 16 + srow) * K + kt + slab * 32 + sg,
                        &Bs[db][h][slab][rg * 16][0]);
        }
    };
    auto loadA = [&](int db, int mq, bf16x8 (&dst)[4][2]) {
        #pragma unroll
        for (int i = 0; i < 4; i++)
            #pragma unroll
            for (int kk = 0; kk < 2; kk++)
                dst[i][kk] = *reinterpret_cast<const bf16x8*>(
                    &As[db][wr][kk][(mq * 4 + i) * 16 + lm][pco]);
    };
    auto loadB = [&](int db, int bq, bf16x8 (&dst)[2][2]) {
        #pragma unroll
        for (int j = 0; j < 2; j++)
            #pragma unroll
            for (int kk = 0; kk < 2; kk++)
                dst[j][kk] = *reinterpret_cast<const bf16x8*>(
                    &Bs[db][wc >> 1][kk][(wc & 1) * 64 + (bq * 2 + j) * 16 + lm][pco]);
    };
    auto quad = [&](int mq, int bq, bf16x8 (&a)[4][2], bf16x8 (&b)[2][2]) {
        #pragma unroll
        for (int kk = 0; kk < 2; kk++)
            #pragma unroll
            for (int i = 0; i < 4; i++)
                #pragma unroll
                for (int j = 0; j < 2; j++)
                    acc[mq * 4 + i][bq * 2 + j] =
                        MFMA_BF16(a[i][kk], b[j][kk], acc[mq * 4 + i][bq * 2 + j]);
    };

#define PHASE_SYNC()                                         \
    __builtin_amdgcn_s_barrier();                            \
    asm volatile("s_waitcnt lgkmcnt(0)" ::: "memory");       \
    __builtin_amdgcn_sched_barrier(0)

    const int NT = K >> 6;
    stageB(0, 0);  stageA(0, 0);
    stageB(1, 64); stageA(1, 64);
    asm volatile("s_waitcnt vmcnt(8)" ::: "memory");
    __builtin_amdgcn_s_barrier();
    __builtin_amdgcn_sched_barrier(0);

    bf16x8 af[4][2], b0[2][2], b1[2][2];
    for (int t = 0; t < NT; ++t) {
        const int db = t & 1;
        const int kt2 = (t + 2) * 64;
        // ---- p0: quad(m-lo, n-lo) ----
        loadA(db, 0, af);
        loadB(db, 0, b0);
        PHASE_SYNC();
        __builtin_amdgcn_s_setprio(1);
        quad(0, 0, af, b0);
        __builtin_amdgcn_s_setprio(0);
        __builtin_amdgcn_s_barrier();
        // ---- p1: quad(m-lo, n-hi) ----
        loadB(db, 1, b1);
        PHASE_SYNC();
        __builtin_amdgcn_s_setprio(1);
        quad(0, 1, af, b1);
        __builtin_amdgcn_s_setprio(0);
        __builtin_amdgcn_s_barrier();
        // ---- p2: quad(m-hi, n-lo); stage B(t+2) into db (B halves free after p1) ----
        loadA(db, 1, af);
        if (t + 2 < NT) stageB(db, kt2);
        PHASE_SYNC();
        __builtin_amdgcn_s_setprio(1);
        quad(1, 0, af, b0);
        __builtin_amdgcn_s_setprio(0);
        __builtin_amdgcn_s_barrier();
        // ---- p3: quad(m-hi, n-hi); stage A(t+2) into db (A halves free after p2); fence ----
        if (t + 2 < NT) {
            stageA(db, kt2);
            asm volatile("s_waitcnt vmcnt(8)" ::: "memory");   // retire all of tile t+1
        } else if (t + 1 < NT) {
            asm volatile("s_waitcnt vmcnt(0)" ::: "memory");   // final drain before last tile
        }
        __builtin_amdgcn_s_barrier();
        __builtin_amdgcn_sched_barrier(0);
        __builtin_amdgcn_s_setprio(1);
        quad(1, 1, af, b1);
        __builtin_amdgcn_s_setprio(0);
        __builtin_amdgcn_s_barrier();
    }
#undef PHASE_SYNC

    const int r0 = bm + wr * 128, c0 = bn + wc * 64;
    #pragma unroll
    for (int mi = 0; mi < 8; mi++)
        #pragma unroll
        for (int ni = 0; ni < 4; ni++)
            #pragma unroll
            for (int e = 0; e < 4; e++) {
                const int row = r0 + mi * 16 + lq * 4 + e;
                const int col = c0 + ni * 16 + lm;
                const float v = acc[mi][ni][e];
                const size_t idx = (size_t)row * N + col;
                if (EPI == 0) outb[idx] = (bf16)v;
                else          outb[idx] = (bf16)gelu_fast(v);
            }
}

// ---------------- GEMM 128x128, 8 waves, BK=64, TRIPLE-buffered, 2 phases/K-tile ----------------
// R5-best fc2/proj kernel (58.9 us fc2) + bijective XCD swizzle (validated R4/R8:
// FETCH 143->57 MB; each XCD's 4 contiguous by-rows of A = 4 MB = its private L2).
// Grid (8, M/128) = 256 blocks (nwg%8==0 required by swizzle), 512 thr -> 8 waves/CU.
// LDS 3 x 32 KB = 96 KB. Zero-conflict 8-wide XOR layout. vmcnt(4) counted fence.
// Epilogue: outf = resid + acc (fp32).
__global__ __launch_bounds__(512, 2)
void gemm128p(const bf16* __restrict__ A, const bf16* __restrict__ Bt,
              const float* __restrict__ resid, float* __restrict__ outf,
              int M, int N, int K) {
    __shared__ bf16 As[3][128][64];
    __shared__ bf16 Bs[3][128][64];
    const int tid = threadIdx.x;
    const int wave = tid >> 6, lane = tid & 63;
    const int lm = lane & 15, lq = lane >> 4;
    const int wm = (wave >> 2) * 64, wn = (wave & 3) * 32;
    // XCD-aware bijective swizzle: blocks resident on XCD x (orig%8==x) get contiguous
    // row-major tile ids swz in [x*nwg/8, (x+1)*nwg/8)
    const int nwg = gridDim.x * gridDim.y;
    const int orig = blockIdx.x + gridDim.x * blockIdx.y;
    const int cpx = nwg >> 3;
    const int swz = (orig & 7) * cpx + (orig >> 3);
    const int bx = swz % gridDim.x, by = swz / gridDim.x;
    const int bm = by * 128, bn = bx * 128;
    const int lr8 = lane >> 3;                       // row 0..7 within 8-row chunk
    const int lg  = ((lane & 7) ^ lr8) * 8;          // XOR-swizzled global col group (bf16)
    const int sa  = lm & 7;
    int co[2];
    co[0] = (lq ^ sa) * 8;                           // phys col, kslab 0
    co[1] = ((lq ^ 4) ^ sa) * 8;                     // phys col, kslab 1
    f32x4 acc[4][2];
    #pragma unroll
    for (int i = 0; i < 4; i++)
        #pragma unroll
        for (int j = 0; j < 2; j++) acc[i][j] = (f32x4){0.f, 0.f, 0.f, 0.f};

    // per wave: 2 chunks of 8 rows per matrix (8 waves x 16 rows = 128 rows)
    auto stageA = [&](int s, int kt) {
        #pragma unroll
        for (int c = 0; c < 2; c++)
            ASYNC16(A + (size_t)(bm + (wave * 2 + c) * 8 + lr8) * K + kt + lg,
                    &As[s][(wave * 2 + c) * 8][0]);
    };
    auto stageB = [&](int s, int kt) {
        #pragma unroll
        for (int c = 0; c < 2; c++)
            ASYNC16(Bt + (size_t)(bn + (wave * 2 + c) * 8 + lr8) * K + kt + lg,
                    &Bs[s][(wave * 2 + c) * 8][0]);
    };

    const int NT = K >> 6;   // K/64 tiles (K >= 128 in all uses)
    stageA(0, 0);  stageB(0, 0);
    stageA(1, 64); stageB(1, 64);
    asm volatile("s_waitcnt vmcnt(4)" ::: "memory");   // tile 0 resident; tile 1 in flight
    __builtin_amdgcn_s_barrier();
    __builtin_amdgcn_sched_barrier(0);

    int s = 0;
    for (int t = 0; t < NT; ++t) {
        const int s2 = (s + 2 >= 3) ? s - 1 : s + 2;   // (t+2) % 3
        const int kt2 = (t + 2) * 64;
        bf16x8 a0[4], b0[2];
        // ---- p0: kslab 0 ----
        #pragma unroll
        for (int mi = 0; mi < 4; mi++)
            a0[mi] = *reinterpret_cast<const bf16x8*>(&As[s][wm + mi * 16 + lm][co[0]]);
        #pragma unroll
        for (int nj = 0; nj < 2; nj++)
            b0[nj] = *reinterpret_cast<const bf16x8*>(&Bs[s][wn + nj * 16 + lm][co[0]]);
        if (t + 2 < NT) stageA(s2, kt2);
        __builtin_amdgcn_s_barrier();
        asm volatile("s_waitcnt lgkmcnt(0)" ::: "memory");
        __builtin_amdgcn_sched_barrier(0);
        __builtin_amdgcn_s_setprio(1);
        #pragma unroll
        for (int mi = 0; mi < 4; mi++)
            #pragma unroll
            for (int nj = 0; nj < 2; nj++)
                acc[mi][nj] = MFMA_BF16(a0[mi], b0[nj], acc[mi][nj]);
        __builtin_amdgcn_s_setprio(0);
        __builtin_amdgcn_s_barrier();
        // ---- p1: kslab 1 ----
        #pragma unroll
        for (int mi = 0; mi < 4; mi++)
            a0[mi] = *reinterpret_cast<const bf16x8*>(&As[s][wm + mi * 16 + lm][co[1]]);
        #pragma unroll
        for (int nj = 0; nj < 2; nj++)
            b0[nj] = *reinterpret_cast<const bf16x8*>(&Bs[s][wn + nj * 16 + lm][co[1]]);
        if (t + 2 < NT) {
            stageB(s2, kt2);
            asm volatile("s_waitcnt vmcnt(4)" ::: "memory");   // retire tile t+1 exactly
        } else if (t + 1 < NT) {
            asm volatile("s_waitcnt vmcnt(0)" ::: "memory");   // drain before last tile
        }
        __builtin_amdgcn_s_barrier();
        asm volatile("s_waitcnt lgkmcnt(0)" ::: "memory");
        __builtin_amdgcn_sched_barrier(0);
        __builtin_amdgcn_s_setprio(1);
        #pragma unroll
        for (int mi = 0; mi < 4; mi++)
            #pragma unroll
            for (int nj = 0; nj < 2; nj++)
                acc[mi][nj] = MFMA_BF16(a0[mi], b0[nj], acc[mi][nj]);
        __builtin_amdgcn_s_setprio(0);
        __builtin_amdgcn_s_barrier();
        s = (s == 2) ? 0 : s + 1;
    }

    const int r0 = bm + wm, c0 = bn + wn;
    #pragma unroll
    for (int i = 0; i < 4; i++)
        #pragma unroll
        for (int j = 0; j < 2; j++)
            #pragma unroll
            for (int e = 0; e < 4; e++) {
                const int row = r0 + i * 16 + lq * 4 + e;
                const int col = c0 + j * 16 + lm;
                const size_t idx = (size_t)row * N + col;
                outf[idx] = resid[idx] + acc[i][j][e];
            }
}

// ---------------- Flash attention, causal, hd=64, T=2048, H=16 ----------------
__global__ __launch_bounds__(256)
void attn_kernel(const bf16* __restrict__ qkv, const bf16* __restrict__ vt,
                 bf16* __restrict__ y) {
    __shared__ bf16 Ks[64][68];        // [key][hd]; stride 34 dw -> 2-way max on b128
    __shared__ bf16 Vt[64][68];        // [hd][key]
    __shared__ bf16 Ps[4][16][68];     // per-wave P tile [qrow][key]
    const int tid = threadIdx.x, wave = tid >> 6, lane = tid & 63;
    const int lm = lane & 15, lq = lane >> 4;
    const int h = blockIdx.y, b = blockIdx.z;
    const size_t base = (size_t)b * 2048 * 3072;
    const bf16* Kbase = qkv + base + 1024 + h * 64;
    const bf16* Vbase = vt + ((size_t)(b * 16 + h) * 64) * 2048;
    const int skey = tid >> 3, sch = (tid & 7) * 8;
    const float k1 = 0.18033688011112042f;   // 0.125 * log2(e)

    bf16x8 ones;
    #pragma unroll
    for (int j = 0; j < 8; j++) ones[j] = (lm == 0) ? (bf16)1.0f : (bf16)0.0f;

    for (int ph = 0; ph < 2; ph++) {
        const int qt = ph ? (int)blockIdx.x : 31 - (int)blockIdx.x;

        const int qrow = qt * 64 + wave * 16 + lm;
        const bf16* qp = qkv + base + (size_t)qrow * 3072 + h * 64 + lq * 8;
        bf16x8 aq0 = *reinterpret_cast<const bf16x8*>(qp);
        bf16x8 aq1 = *reinterpret_cast<const bf16x8*>(qp + 32);
        #pragma unroll
        for (int j = 0; j < 8; j++) {
            aq0[j] = (bf16)((float)aq0[j] * k1);
            aq1[j] = (bf16)((float)aq1[j] * k1);
        }

        f32x4 Oc[4], Ol;
        #pragma unroll
        for (int nt = 0; nt < 4; nt++) Oc[nt] = (f32x4){0.f, 0.f, 0.f, 0.f};
        Ol = (f32x4){0.f, 0.f, 0.f, 0.f};

        bf16x8 pk0, pk1, pv0, pv1;
        {   // prefetch tile 0
            const bf16* kp = Kbase + (size_t)skey * 3072 + sch;
            pk0 = *reinterpret_cast<const bf16x8*>(kp);
            pk1 = *reinterpret_cast<const bf16x8*>(kp + (size_t)32 * 3072);
            const bf16* vp = Vbase + (size_t)skey * 2048 + sch;
            pv0 = *reinterpret_cast<const bf16x8*>(vp);
            pv1 = *reinterpret_cast<const bf16x8*>(vp + (size_t)32 * 2048);
        }

        for (int kt2 = 0; kt2 <= qt; kt2++) {
            __syncthreads();   // previous iteration/phase LDS reads complete
            *reinterpret_cast<bf16x8*>(&Ks[skey][sch])      = pk0;
            *reinterpret_cast<bf16x8*>(&Ks[skey + 32][sch]) = pk1;
            *reinterpret_cast<bf16x8*>(&Vt[skey][sch])      = pv0;
            *reinterpret_cast<bf16x8*>(&Vt[skey + 32][sch]) = pv1;
            __syncthreads();
            if (kt2 < qt) {   // next-tile loads overlap compute
                const bf16* kp = Kbase + (size_t)((kt2 + 1) * 64 + skey) * 3072 + sch;
                pk0 = *reinterpret_cast<const bf16x8*>(kp);
                pk1 = *reinterpret_cast<const bf16x8*>(kp + (size_t)32 * 3072);
                const bf16* vp = Vbase + (size_t)skey * 2048 + (kt2 + 1) * 64 + sch;
                pv0 = *reinterpret_cast<const bf16x8*>(vp);
                pv1 = *reinterpret_cast<const bf16x8*>(vp + (size_t)32 * 2048);
            }

            f32x4 Sc[4];
            #pragma unroll
            for (int nt = 0; nt < 4; nt++) Sc[nt] = (f32x4){0.f, 0.f, 0.f, 0.f};
            #pragma unroll
            for (int nt = 0; nt < 4; nt++) {
                const bf16x8 bk0 = *reinterpret_cast<const bf16x8*>(&Ks[nt * 16 + lm][lq * 8]);
                const bf16x8 bk1 = *reinterpret_cast<const bf16x8*>(&Ks[nt * 16 + lm][32 + lq * 8]);
                Sc[nt] = MFMA_BF16(aq0, bk0, Sc[nt]);
                Sc[nt] = MFMA_BF16(aq1, bk1, Sc[nt]);
            }

            // fixed-shift softmax: p = exp2(score); masked -> 0
            const int qb = wave * 16 + lq * 4;
            #pragma unroll
            for (int e = 0; e < 4; e++) {
                #pragma unroll
                for (int nt = 0; nt < 4; nt++) {
                    float sv = Sc[nt][e];
                    if (kt2 == qt && (nt * 16 + lm) > (qb + e)) sv = -1e30f;
                    Ps[wave][lq * 4 + e][nt * 16 + lm] = (bf16)exp2f(sv);
                }
            }

            const bf16x8 ap0 = *reinterpret_cast<const bf16x8*>(&Ps[wave][lm][lq * 8]);
            const bf16x8 ap1 = *reinterpret_cast<const bf16x8*>(&Ps[wave][lm][32 + lq * 8]);
            Ol = MFMA_BF16(ap0, ones, Ol);      // row-sum l into column 0
            Ol = MFMA_BF16(ap1, ones, Ol);
            #pragma unroll
            for (int nt = 0; nt < 4; nt++) {
                const bf16x8 bv0 = *reinterpret_cast<const bf16x8*>(&Vt[nt * 16 + lm][lq * 8]);
                const bf16x8 bv1 = *reinterpret_cast<const bf16x8*>(&Vt[nt * 16 + lm][32 + lq * 8]);
                Oc[nt] = MFMA_BF16(ap0, bv0, Oc[nt]);
                Oc[nt] = MFMA_BF16(ap1, bv1, Oc[nt]);
            }
        }

        const int qrow0 = qt * 64 + wave * 16 + lq * 4;
        float inv[4];
        #pragma unroll
        for (int e = 0; e < 4; e++) inv[e] = 1.0f / __shfl(Ol[e], lane & 48);
        #pragma unroll
        for (int nt = 0; nt < 4; nt++)
            #pragma unroll
            for (int e = 0; e < 4; e++) {
                const int row = qrow0 + e;
                y[((size_t)b * 2048 + row) * 1024 + h * 64 + nt * 16 + lm] = (bf16)(Oc[nt][e] * inv[e]);
            }
    }
}

// ---------------- launcher ----------------
extern "C" void kernel_launch(void* const* d_in, const int* in_sizes, int n_in,
                              void* d_out, int out_size, void* d_ws, size_t ws_size,
                              hipStream_t stream) {
    const float* x     = (const float*)d_in[0];
    const float* Wqkv  = (const float*)d_in[1];
    const float* Wproj = (const float*)d_in[2];
    const float* Wfc1  = (const float*)d_in[3];
    const float* Wfc2  = (const float*)d_in[4];
    const float* ln1g  = (const float*)d_in[5];
    const float* ln1b  = (const float*)d_in[6];
    const float* ln2g  = (const float*)d_in[7];
    const float* ln2b  = (const float*)d_in[8];
    float* out = (float*)d_out;
    char* ws = (char*)d_ws;

    bf16*  Wqkvt  = (bf16*)(ws);                  //  6 MB [3072][1024]
    bf16*  Wprojt = (bf16*)(ws + 6291456);        //  2 MB [1024][1024]
    bf16*  Wfc1t  = (bf16*)(ws + 8388608);        //  8 MB [4096][1024]
    bf16*  Wfc2t  = (bf16*)(ws + 16777216);       //  8 MB [1024][4096]
    bf16*  hb     = (bf16*)(ws + 25165824);       //  8 MB LN out; dead after qkv GEMM
    bf16*  vt     = (bf16*)(ws + 25165824);       //  8 MB V^T (aliases hb; reused for LN2)
    bf16*  qkv    = (bf16*)(ws + 33554432);       // 24 MB [4096][3072]
    bf16*  yb     = (bf16*)(ws + 58720256);       //  8 MB attn out [4096][1024]
    float* x1     = (float*)(ws + 67108864);      // 16 MB residual fp32
    bf16*  h3     = (bf16*)(ws + 33554432);       // 32 MB gelu out (aliases dead qkv+yb)

    const dim3 tb(32, 8);
    transpose_cast<<<dim3(96, 32), tb, 0, stream>>>(Wqkv, Wqkvt, 1024, 3072);
    transpose_cast<<<dim3(32, 32), tb, 0, stream>>>(Wproj, Wprojt, 1024, 1024);
    transpose_cast<<<dim3(128, 32), tb, 0, stream>>>(Wfc1, Wfc1t, 1024, 4096);
    transpose_cast<<<dim3(32, 128), tb, 0, stream>>>(Wfc2, Wfc2t, 4096, 1024);

    ln_kernel<<<dim3(4096), dim3(256), 0, stream>>>(x, ln1g, ln1b, hb);
    gemm256<0><<<dim3(12, 16), dim3(512), 0, stream>>>(hb, Wqkvt, qkv, 4096, 3072, 1024);
    transpose_v<<<dim3(64, 2, 32), tb, 0, stream>>>(qkv, vt);
    attn_kernel<<<dim3(16, 16, 2), dim3(256), 0, stream>>>(qkv, vt, yb);
    gemm128p<<<dim3(8, 32), dim3(512), 0, stream>>>(yb, Wprojt, x, x1, 4096, 1024, 1024);
    ln_kernel<<<dim3(4096), dim3(256), 0, stream>>>(x1, ln2g, ln2b, hb);
    gemm256<2><<<dim3(16, 16), dim3(512), 0, stream>>>(hb, Wfc1t, h3, 4096, 4096, 1024);
    gemm128p<<<dim3(8, 32), dim3(512), 0, stream>>>(h3, Wfc2t, x1, out, 4096, 1024, 4096);
}

// Round 10
// 325.772 us; speedup vs baseline: 1.1579x; 1.0322x over previous
//
#include <hip/hip_runtime.h>
#include <hip/hip_bf16.h>
#include <math.h>

typedef __bf16 bf16;
typedef __bf16 bf16x4 __attribute__((ext_vector_type(4)));
typedef __bf16 bf16x8 __attribute__((ext_vector_type(8)));
typedef float f32x4 __attribute__((ext_vector_type(4)));
typedef unsigned int u32;

#define MFMA_BF16(a, b, c) __builtin_amdgcn_mfma_f32_16x16x32_bf16(a, b, c, 0, 0, 0)
// async global->LDS, 16B per lane; LDS dest = wave-uniform base + lane*16
#define ASYNC16(g, l)                                                                   \
    __builtin_amdgcn_global_load_lds((const __attribute__((address_space(1))) u32*)(g), \
                                     (__attribute__((address_space(3))) u32*)(l), 16, 0, 0)

// ---------------- fused prologue: 4x transpose_cast + ln1 in ONE launch ----------------
// Blocks 0..12287: weight transposes (fp32 -> bf16, out[c][r]=in[r][c], 32x32 tiles)
//   [0,3072)   Wqkv  1024x3072 -> 96x32 tiles
//   [3072,4096) Wproj 1024x1024 -> 32x32
//   [4096,8192) Wfc1  1024x4096 -> 128x32
//   [8192,12288) Wfc2 4096x1024 -> 32x128
// Blocks 12288..16383: LayerNorm1 rows (x -> hb), one block per row.
// Branch is block-uniform; saves 4 inter-launch gaps (~4 us each, R2 accounting).
__global__ __launch_bounds__(256)
void prep_kernel(const float* __restrict__ Wqkv, const float* __restrict__ Wproj,
                 const float* __restrict__ Wfc1, const float* __restrict__ Wfc2,
                 bf16* __restrict__ Wqkvt, bf16* __restrict__ Wprojt,
                 bf16* __restrict__ Wfc1t, bf16* __restrict__ Wfc2t,
                 const float* __restrict__ x, const float* __restrict__ g,
                 const float* __restrict__ bb, bf16* __restrict__ hb) {
    const int blk = blockIdx.x;
    const int tid = threadIdx.x;
    if (blk < 12288) {
        __shared__ float tile[32][33];
        const float* in; bf16* out; int rows, cols, bx, by;
        if (blk < 3072)      { in = Wqkv;  out = Wqkvt;  rows = 1024; cols = 3072; const int r = blk;        bx = r % 96;  by = r / 96; }
        else if (blk < 4096) { in = Wproj; out = Wprojt; rows = 1024; cols = 1024; const int r = blk - 3072; bx = r % 32;  by = r / 32; }
        else if (blk < 8192) { in = Wfc1;  out = Wfc1t;  rows = 1024; cols = 4096; const int r = blk - 4096; bx = r % 128; by = r / 128; }
        else                 { in = Wfc2;  out = Wfc2t;  rows = 4096; cols = 1024; const int r = blk - 8192; bx = r % 32;  by = r / 32; }
        const int tx = tid & 31, ty = tid >> 5;
        const int c0 = bx * 32, r0 = by * 32;
        #pragma unroll
        for (int j = 0; j < 4; j++)
            tile[ty + j * 8][tx] = in[(size_t)(r0 + ty + j * 8) * cols + c0 + tx];
        __syncthreads();
        #pragma unroll
        for (int j = 0; j < 4; j++)
            out[(size_t)(c0 + ty + j * 8) * rows + r0 + tx] = (bf16)tile[tx][ty + j * 8];
    } else {
        const int row = blk - 12288;
        const float4 v = reinterpret_cast<const float4*>(x)[(size_t)row * 256 + tid];
        float s = v.x + v.y + v.z + v.w;
        float sq = v.x * v.x + v.y * v.y + v.z * v.z + v.w * v.w;
        #pragma unroll
        for (int o = 32; o > 0; o >>= 1) { s += __shfl_xor(s, o); sq += __shfl_xor(sq, o); }
        __shared__ float ssum[4], ssq[4];
        const int wave = tid >> 6, lane = tid & 63;
        if (lane == 0) { ssum[wave] = s; ssq[wave] = sq; }
        __syncthreads();
        s = ssum[0] + ssum[1] + ssum[2] + ssum[3];
        sq = ssq[0] + ssq[1] + ssq[2] + ssq[3];
        const float mean = s * (1.0f / 1024.0f);
        const float var = sq * (1.0f / 1024.0f) - mean * mean;
        const float rstd = rsqrtf(var + 1e-5f);
        const float4 gv = reinterpret_cast<const float4*>(g)[tid];
        const float4 bv = reinterpret_cast<const float4*>(bb)[tid];
        bf16x4 o;
        o[0] = (bf16)((v.x - mean) * rstd * gv.x + bv.x);
        o[1] = (bf16)((v.y - mean) * rstd * gv.y + bv.y);
        o[2] = (bf16)((v.z - mean) * rstd * gv.z + bv.z);
        o[3] = (bf16)((v.w - mean) * rstd * gv.w + bv.w);
        reinterpret_cast<bf16x4*>(hb)[(size_t)row * 256 + tid] = o;
    }
}

// ---------------- transpose V out of qkv: vt[(b*16+h)*64+d][t] = qkv[b][t][2048+h*64+d] ----------------
__global__ __launch_bounds__(256)
void transpose_v(const bf16* __restrict__ qkv, bf16* __restrict__ vt) {
    __shared__ bf16 tile[32][33];
    const int tx = threadIdx.x, ty = threadIdx.y;  // (32,8)
    const int t0 = blockIdx.x * 32;
    const int d0 = blockIdx.y * 32;
    const int bh = blockIdx.z;
    const int b = bh >> 4, h = bh & 15;
    const bf16* src = qkv + (size_t)b * 2048 * 3072 + 2048 + h * 64;
    #pragma unroll
    for (int j = 0; j < 4; j++)
        tile[ty + j * 8][tx] = src[(size_t)(t0 + ty + j * 8) * 3072 + d0 + tx];
    __syncthreads();
    #pragma unroll
    for (int j = 0; j < 4; j++)
        vt[((size_t)bh * 64 + d0 + ty + j * 8) * 2048 + t0 + tx] = tile[tx][ty + j * 8];
}

// ---------------- LayerNorm fp32 -> bf16, D=1024, one block per row (ln2) ----------------
__global__ __launch_bounds__(256)
void ln_kernel(const float* __restrict__ x, const float* __restrict__ g,
               const float* __restrict__ bb, bf16* __restrict__ out) {
    const int row = blockIdx.x, tid = threadIdx.x;
    const float4 v = reinterpret_cast<const float4*>(x)[(size_t)row * 256 + tid];
    float s = v.x + v.y + v.z + v.w;
    float sq = v.x * v.x + v.y * v.y + v.z * v.z + v.w * v.w;
    #pragma unroll
    for (int o = 32; o > 0; o >>= 1) { s += __shfl_xor(s, o); sq += __shfl_xor(sq, o); }
    __shared__ float ssum[4], ssq[4];
    const int wave = tid >> 6, lane = tid & 63;
    if (lane == 0) { ssum[wave] = s; ssq[wave] = sq; }
    __syncthreads();
    s = ssum[0] + ssum[1] + ssum[2] + ssum[3];
    sq = ssq[0] + ssq[1] + ssq[2] + ssq[3];
    const float mean = s * (1.0f / 1024.0f);
    const float var = sq * (1.0f / 1024.0f) - mean * mean;
    const float rstd = rsqrtf(var + 1e-5f);
    const float4 gv = reinterpret_cast<const float4*>(g)[tid];
    const float4 bv = reinterpret_cast<const float4*>(bb)[tid];
    bf16x4 o;
    o[0] = (bf16)((v.x - mean) * rstd * gv.x + bv.x);
    o[1] = (bf16)((v.y - mean) * rstd * gv.y + bv.y);
    o[2] = (bf16)((v.z - mean) * rstd * gv.z + bv.z);
    o[3] = (bf16)((v.w - mean) * rstd * gv.w + bv.w);
    reinterpret_cast<bf16x4*>(out)[(size_t)row * 256 + tid] = o;
}

// fast exact-enough GELU: v * sigmoid(1.595769122*(v + 0.044715 v^3)); max dev vs erf-gelu ~3e-4
__device__ __forceinline__ float gelu_fast(float v) {
    const float vv = v * v;
    const float u = v * (1.595769122f + 0.0713548162726f * vv);
    const float t = exp2f(u * -1.4426950408889634f);   // e^{-u}
    return v / (1.0f + t);
}

// ---------------- GEMM 256x256 tile, 8-phase schedule (unchanged — qkv/fc1) ----
template <int EPI>
__global__ __launch_bounds__(512, 1)
void gemm256(const bf16* __restrict__ A, const bf16* __restrict__ Bt,
             bf16* __restrict__ outb, int M, int N, int K) {
    __shared__ bf16 As[2][2][2][128][32];   // [dbuf][Mhalf][kslab][row][32k]
    __shared__ bf16 Bs[2][2][2][128][32];   // [dbuf][Nhalf][kslab][row][32k]
    const int tid = threadIdx.x;
    const int wave = tid >> 6, lane = tid & 63;
    const int lm = lane & 15, lq = lane >> 4;
    const int wr = wave >> 2, wc = wave & 3;           // wave tile: (wr*128, wc*64)
    const int bm = blockIdx.y * 256, bn = blockIdx.x * 256;
    const int srow = lane >> 2;                              // staging row 0..15
    const int sg = (((lane & 3) ^ ((lane >> 3) & 3)) * 8);   // swizzled source col (bf16)
    const int pco = (lq ^ ((lm >> 1) & 3)) * 8;              // reader phys col (bf16)

    f32x4 acc[8][4];
    #pragma unroll
    for (int i = 0; i < 8; i++)
        #pragma unroll
        for (int j = 0; j < 4; j++) acc[i][j] = (f32x4){0.f, 0.f, 0.f, 0.f};

    auto stageA = [&](int db, int kt) {
        #pragma unroll
        for (int L = 0; L < 2; L++) {
            const int g = wave * 2 + L, slab = g >> 3, rg = g & 7;
            #pragma unroll
            for (int h = 0; h < 2; h++)
                ASYNC16(A + (size_t)(bm + h * 128 + rg * 16 + srow) * K + kt + slab * 32 + sg,
                        &As[db][h][slab][rg * 16][0]);
        }
    };
    auto stageB = [&](int db, int kt) {
        #pragma unroll
        for (int L = 0; L < 2; L++) {
            const int g = wave * 2 + L, slab = g >> 3, rg = g & 7;
            #pragma unroll
            for (int h = 0; h < 2; h++)
                ASYNC16(Bt + (size_t)(bn + h * 128 + rg * 16 + srow) * K + kt + slab * 32 + sg,
                        &Bs[db][h][slab][rg * 16][0]);
        }
    };
    auto loadA = [&](int db, int mq, bf16x8 (&dst)[4][2]) {
        #pragma unroll
        for (int i = 0; i < 4; i++)
            #pragma unroll
            for (int kk = 0; kk < 2; kk++)
                dst[i][kk] = *reinterpret_cast<const bf16x8*>(
                    &As[db][wr][kk][(mq * 4 + i) * 16 + lm][pco]);
    };
    auto loadB = [&](int db, int bq, bf16x8 (&dst)[2][2]) {
        #pragma unroll
        for (int j = 0; j < 2; j++)
            #pragma unroll
            for (int kk = 0; kk < 2; kk++)
                dst[j][kk] = *reinterpret_cast<const bf16x8*>(
                    &Bs[db][wc >> 1][kk][(wc & 1) * 64 + (bq * 2 + j) * 16 + lm][pco]);
    };
    auto quad = [&](int mq, int bq, bf16x8 (&a)[4][2], bf16x8 (&b)[2][2]) {
        #pragma unroll
        for (int kk = 0; kk < 2; kk++)
            #pragma unroll
            for (int i = 0; i < 4; i++)
                #pragma unroll
                for (int j = 0; j < 2; j++)
                    acc[mq * 4 + i][bq * 2 + j] =
                        MFMA_BF16(a[i][kk], b[j][kk], acc[mq * 4 + i][bq * 2 + j]);
    };

#define PHASE_SYNC()                                         \
    __builtin_amdgcn_s_barrier();                            \
    asm volatile("s_waitcnt lgkmcnt(0)" ::: "memory");       \
    __builtin_amdgcn_sched_barrier(0)

    const int NT = K >> 6;
    stageB(0, 0);  stageA(0, 0);
    stageB(1, 64); stageA(1, 64);
    asm volatile("s_waitcnt vmcnt(8)" ::: "memory");
    __builtin_amdgcn_s_barrier();
    __builtin_amdgcn_sched_barrier(0);

    bf16x8 af[4][2], b0[2][2], b1[2][2];
    for (int t = 0; t < NT; ++t) {
        const int db = t & 1;
        const int kt2 = (t + 2) * 64;
        // ---- p0: quad(m-lo, n-lo) ----
        loadA(db, 0, af);
        loadB(db, 0, b0);
        PHASE_SYNC();
        __builtin_amdgcn_s_setprio(1);
        quad(0, 0, af, b0);
        __builtin_amdgcn_s_setprio(0);
        __builtin_amdgcn_s_barrier();
        // ---- p1: quad(m-lo, n-hi) ----
        loadB(db, 1, b1);
        PHASE_SYNC();
        __builtin_amdgcn_s_setprio(1);
        quad(0, 1, af, b1);
        __builtin_amdgcn_s_setprio(0);
        __builtin_amdgcn_s_barrier();
        // ---- p2: quad(m-hi, n-lo); stage B(t+2) into db (B halves free after p1) ----
        loadA(db, 1, af);
        if (t + 2 < NT) stageB(db, kt2);
        PHASE_SYNC();
        __builtin_amdgcn_s_setprio(1);
        quad(1, 0, af, b0);
        __builtin_amdgcn_s_setprio(0);
        __builtin_amdgcn_s_barrier();
        // ---- p3: quad(m-hi, n-hi); stage A(t+2) into db (A halves free after p2); fence ----
        if (t + 2 < NT) {
            stageA(db, kt2);
            asm volatile("s_waitcnt vmcnt(8)" ::: "memory");   // retire all of tile t+1
        } else if (t + 1 < NT) {
            asm volatile("s_waitcnt vmcnt(0)" ::: "memory");   // final drain before last tile
        }
        __builtin_amdgcn_s_barrier();
        __builtin_amdgcn_sched_barrier(0);
        __builtin_amdgcn_s_setprio(1);
        quad(1, 1, af, b1);
        __builtin_amdgcn_s_setprio(0);
        __builtin_amdgcn_s_barrier();
    }
#undef PHASE_SYNC

    const int r0 = bm + wr * 128, c0 = bn + wc * 64;
    #pragma unroll
    for (int mi = 0; mi < 8; mi++)
        #pragma unroll
        for (int ni = 0; ni < 4; ni++)
            #pragma unroll
            for (int e = 0; e < 4; e++) {
                const int row = r0 + mi * 16 + lq * 4 + e;
                const int col = c0 + ni * 16 + lm;
                const float v = acc[mi][ni][e];
                const size_t idx = (size_t)row * N + col;
                if (EPI == 0) outb[idx] = (bf16)v;
                else          outb[idx] = (bf16)gelu_fast(v);
            }
}

// ---------------- GEMM 128x128, 8 waves, BK=64, TRIPLE-buffered, 2 phases/K-tile ----------------
// R9-best fc2/proj kernel (55 us fc2) with bijective XCD swizzle (FETCH = compulsory 57 MB).
__global__ __launch_bounds__(512, 2)
void gemm128p(const bf16* __restrict__ A, const bf16* __restrict__ Bt,
              const float* __restrict__ resid, float* __restrict__ outf,
              int M, int N, int K) {
    __shared__ bf16 As[3][128][64];
    __shared__ bf16 Bs[3][128][64];
    const int tid = threadIdx.x;
    const int wave = tid >> 6, lane = tid & 63;
    const int lm = lane & 15, lq = lane >> 4;
    const int wm = (wave >> 2) * 64, wn = (wave & 3) * 32;
    const int nwg = gridDim.x * gridDim.y;
    const int orig = blockIdx.x + gridDim.x * blockIdx.y;
    const int cpx = nwg >> 3;
    const int swz = (orig & 7) * cpx + (orig >> 3);
    const int bx = swz % gridDim.x, by = swz / gridDim.x;
    const int bm = by * 128, bn = bx * 128;
    const int lr8 = lane >> 3;                       // row 0..7 within 8-row chunk
    const int lg  = ((lane & 7) ^ lr8) * 8;          // XOR-swizzled global col group (bf16)
    const int sa  = lm & 7;
    int co[2];
    co[0] = (lq ^ sa) * 8;                           // phys col, kslab 0
    co[1] = ((lq ^ 4) ^ sa) * 8;                     // phys col, kslab 1
    f32x4 acc[4][2];
    #pragma unroll
    for (int i = 0; i < 4; i++)
        #pragma unroll
        for (int j = 0; j < 2; j++) acc[i][j] = (f32x4){0.f, 0.f, 0.f, 0.f};

    auto stageA = [&](int s, int kt) {
        #pragma unroll
        for (int c = 0; c < 2; c++)
            ASYNC16(A + (size_t)(bm + (wave * 2 + c) * 8 + lr8) * K + kt + lg,
                    &As[s][(wave * 2 + c) * 8][0]);
    };
    auto stageB = [&](int s, int kt) {
        #pragma unroll
        for (int c = 0; c < 2; c++)
            ASYNC16(Bt + (size_t)(bn + (wave * 2 + c) * 8 + lr8) * K + kt + lg,
                    &Bs[s][(wave * 2 + c) * 8][0]);
    };

    const int NT = K >> 6;   // K/64 tiles (K >= 128 in all uses)
    stageA(0, 0);  stageB(0, 0);
    stageA(1, 64); stageB(1, 64);
    asm volatile("s_waitcnt vmcnt(4)" ::: "memory");   // tile 0 resident; tile 1 in flight
    __builtin_amdgcn_s_barrier();
    __builtin_amdgcn_sched_barrier(0);

    int s = 0;
    for (int t = 0; t < NT; ++t) {
        const int s2 = (s + 2 >= 3) ? s - 1 : s + 2;   // (t+2) % 3
        const int kt2 = (t + 2) * 64;
        bf16x8 a0[4], b0[2];
        // ---- p0: kslab 0 ----
        #pragma unroll
        for (int mi = 0; mi < 4; mi++)
            a0[mi] = *reinterpret_cast<const bf16x8*>(&As[s][wm + mi * 16 + lm][co[0]]);
        #pragma unroll
        for (int nj = 0; nj < 2; nj++)
            b0[nj] = *reinterpret_cast<const bf16x8*>(&Bs[s][wn + nj * 16 + lm][co[0]]);
        if (t + 2 < NT) stageA(s2, kt2);
        __builtin_amdgcn_s_barrier();
        asm volatile("s_waitcnt lgkmcnt(0)" ::: "memory");
        __builtin_amdgcn_sched_barrier(0);
        __builtin_amdgcn_s_setprio(1);
        #pragma unroll
        for (int mi = 0; mi < 4; mi++)
            #pragma unroll
            for (int nj = 0; nj < 2; nj++)
                acc[mi][nj] = MFMA_BF16(a0[mi], b0[nj], acc[mi][nj]);
        __builtin_amdgcn_s_setprio(0);
        __builtin_amdgcn_s_barrier();
        // ---- p1: kslab 1 ----
        #pragma unroll
        for (int mi = 0; mi < 4; mi++)
            a0[mi] = *reinterpret_cast<const bf16x8*>(&As[s][wm + mi * 16 + lm][co[1]]);
        #pragma unroll
        for (int nj = 0; nj < 2; nj++)
            b0[nj] = *reinterpret_cast<const bf16x8*>(&Bs[s][wn + nj * 16 + lm][co[1]]);
        if (t + 2 < NT) {
            stageB(s2, kt2);
            asm volatile("s_waitcnt vmcnt(4)" ::: "memory");   // retire tile t+1 exactly
        } else if (t + 1 < NT) {
            asm volatile("s_waitcnt vmcnt(0)" ::: "memory");   // drain before last tile
        }
        __builtin_amdgcn_s_barrier();
        asm volatile("s_waitcnt lgkmcnt(0)" ::: "memory");
        __builtin_amdgcn_sched_barrier(0);
        __builtin_amdgcn_s_setprio(1);
        #pragma unroll
        for (int mi = 0; mi < 4; mi++)
            #pragma unroll
            for (int nj = 0; nj < 2; nj++)
                acc[mi][nj] = MFMA_BF16(a0[mi], b0[nj], acc[mi][nj]);
        __builtin_amdgcn_s_setprio(0);
        __builtin_amdgcn_s_barrier();
        s = (s == 2) ? 0 : s + 1;
    }

    const int r0 = bm + wm, c0 = bn + wn;
    #pragma unroll
    for (int i = 0; i < 4; i++)
        #pragma unroll
        for (int j = 0; j < 2; j++)
            #pragma unroll
            for (int e = 0; e < 4; e++) {
                const int row = r0 + i * 16 + lq * 4 + e;
                const int col = c0 + j * 16 + lm;
                const size_t idx = (size_t)row * N + col;
                outf[idx] = resid[idx] + acc[i][j][e];
            }
}

// ---------------- Flash attention, causal, hd=64, T=2048, H=16 ----------------
__global__ __launch_bounds__(256)
void attn_kernel(const bf16* __restrict__ qkv, const bf16* __restrict__ vt,
                 bf16* __restrict__ y) {
    __shared__ bf16 Ks[64][68];        // [key][hd]; stride 34 dw -> 2-way max on b128
    __shared__ bf16 Vt[64][68];        // [hd][key]
    __shared__ bf16 Ps[4][16][68];     // per-wave P tile [qrow][key]
    const int tid = threadIdx.x, wave = tid >> 6, lane = tid & 63;
    const int lm = lane & 15, lq = lane >> 4;
    const int h = blockIdx.y, b = blockIdx.z;
    const size_t base = (size_t)b * 2048 * 3072;
    const bf16* Kbase = qkv + base + 1024 + h * 64;
    const bf16* Vbase = vt + ((size_t)(b * 16 + h) * 64) * 2048;
    const int skey = tid >> 3, sch = (tid & 7) * 8;
    const float k1 = 0.18033688011112042f;   // 0.125 * log2(e)

    bf16x8 ones;
    #pragma unroll
    for (int j = 0; j < 8; j++) ones[j] = (lm == 0) ? (bf16)1.0f : (bf16)0.0f;

    for (int ph = 0; ph < 2; ph++) {
        const int qt = ph ? (int)blockIdx.x : 31 - (int)blockIdx.x;

        const int qrow = qt * 64 + wave * 16 + lm;
        const bf16* qp = qkv + base + (size_t)qrow * 3072 + h * 64 + lq * 8;
        bf16x8 aq0 = *reinterpret_cast<const bf16x8*>(qp);
        bf16x8 aq1 = *reinterpret_cast<const bf16x8*>(qp + 32);
        #pragma unroll
        for (int j = 0; j < 8; j++) {
            aq0[j] = (bf16)((float)aq0[j] * k1);
            aq1[j] = (bf16)((float)aq1[j] * k1);
        }

        f32x4 Oc[4], Ol;
        #pragma unroll
        for (int nt = 0; nt < 4; nt++) Oc[nt] = (f32x4){0.f, 0.f, 0.f, 0.f};
        Ol = (f32x4){0.f, 0.f, 0.f, 0.f};

        bf16x8 pk0, pk1, pv0, pv1;
        {   // prefetch tile 0
            const bf16* kp = Kbase + (size_t)skey * 3072 + sch;
            pk0 = *reinterpret_cast<const bf16x8*>(kp);
            pk1 = *reinterpret_cast<const bf16x8*>(kp + (size_t)32 * 3072);
            const bf16* vp = Vbase + (size_t)skey * 2048 + sch;
            pv0 = *reinterpret_cast<const bf16x8*>(vp);
            pv1 = *reinterpret_cast<const bf16x8*>(vp + (size_t)32 * 2048);
        }

        for (int kt2 = 0; kt2 <= qt; kt2++) {
            __syncthreads();   // previous iteration/phase LDS reads complete
            *reinterpret_cast<bf16x8*>(&Ks[skey][sch])      = pk0;
            *reinterpret_cast<bf16x8*>(&Ks[skey + 32][sch]) = pk1;
            *reinterpret_cast<bf16x8*>(&Vt[skey][sch])      = pv0;
            *reinterpret_cast<bf16x8*>(&Vt[skey + 32][sch]) = pv1;
            __syncthreads();
            if (kt2 < qt) {   // next-tile loads overlap compute
                const bf16* kp = Kbase + (size_t)((kt2 + 1) * 64 + skey) * 3072 + sch;
                pk0 = *reinterpret_cast<const bf16x8*>(kp);
                pk1 = *reinterpret_cast<const bf16x8*>(kp + (size_t)32 * 3072);
                const bf16* vp = Vbase + (size_t)skey * 2048 + (kt2 + 1) * 64 + sch;
                pv0 = *reinterpret_cast<const bf16x8*>(vp);
                pv1 = *reinterpret_cast<const bf16x8*>(vp + (size_t)32 * 2048);
            }

            f32x4 Sc[4];
            #pragma unroll
            for (int nt = 0; nt < 4; nt++) Sc[nt] = (f32x4){0.f, 0.f, 0.f, 0.f};
            #pragma unroll
            for (int nt = 0; nt < 4; nt++) {
                const bf16x8 bk0 = *reinterpret_cast<const bf16x8*>(&Ks[nt * 16 + lm][lq * 8]);
                const bf16x8 bk1 = *reinterpret_cast<const bf16x8*>(&Ks[nt * 16 + lm][32 + lq * 8]);
                Sc[nt] = MFMA_BF16(aq0, bk0, Sc[nt]);
                Sc[nt] = MFMA_BF16(aq1, bk1, Sc[nt]);
            }

            // fixed-shift softmax: p = exp2(score); masked -> 0
            const int qb = wave * 16 + lq * 4;
            #pragma unroll
            for (int e = 0; e < 4; e++) {
                #pragma unroll
                for (int nt = 0; nt < 4; nt++) {
                    float sv = Sc[nt][e];
                    if (kt2 == qt && (nt * 16 + lm) > (qb + e)) sv = -1e30f;
                    Ps[wave][lq * 4 + e][nt * 16 + lm] = (bf16)exp2f(sv);
                }
            }

            const bf16x8 ap0 = *reinterpret_cast<const bf16x8*>(&Ps[wave][lm][lq * 8]);
            const bf16x8 ap1 = *reinterpret_cast<const bf16x8*>(&Ps[wave][lm][32 + lq * 8]);
            Ol = MFMA_BF16(ap0, ones, Ol);      // row-sum l into column 0
            Ol = MFMA_BF16(ap1, ones, Ol);
            #pragma unroll
            for (int nt = 0; nt < 4; nt++) {
                const bf16x8 bv0 = *reinterpret_cast<const bf16x8*>(&Vt[nt * 16 + lm][lq * 8]);
                const bf16x8 bv1 = *reinterpret_cast<const bf16x8*>(&Vt[nt * 16 + lm][32 + lq * 8]);
                Oc[nt] = MFMA_BF16(ap0, bv0, Oc[nt]);
                Oc[nt] = MFMA_BF16(ap1, bv1, Oc[nt]);
            }
        }

        const int qrow0 = qt * 64 + wave * 16 + lq * 4;
        float inv[4];
        #pragma unroll
        for (int e = 0; e < 4; e++) inv[e] = 1.0f / __shfl(Ol[e], lane & 48);
        #pragma unroll
        for (int nt = 0; nt < 4; nt++)
            #pragma unroll
            for (int e = 0; e < 4; e++) {
                const int row = qrow0 + e;
                y[((size_t)b * 2048 + row) * 1024 + h * 64 + nt * 16 + lm] = (bf16)(Oc[nt][e] * inv[e]);
            }
    }
}

// ---------------- launcher ----------------
extern "C" void kernel_launch(void* const* d_in, const int* in_sizes, int n_in,
                              void* d_out, int out_size, void* d_ws, size_t ws_size,
                              hipStream_t stream) {
    const float* x     = (const float*)d_in[0];
    const float* Wqkv  = (const float*)d_in[1];
    const float* Wproj = (const float*)d_in[2];
    const float* Wfc1  = (const float*)d_in[3];
    const float* Wfc2  = (const float*)d_in[4];
    const float* ln1g  = (const float*)d_in[5];
    const float* ln1b  = (const float*)d_in[6];
    const float* ln2g  = (const float*)d_in[7];
    const float* ln2b  = (const float*)d_in[8];
    float* out = (float*)d_out;
    char* ws = (char*)d_ws;

    bf16*  Wqkvt  = (bf16*)(ws);                  //  6 MB [3072][1024]
    bf16*  Wprojt = (bf16*)(ws + 6291456);        //  2 MB [1024][1024]
    bf16*  Wfc1t  = (bf16*)(ws + 8388608);        //  8 MB [4096][1024]
    bf16*  Wfc2t  = (bf16*)(ws + 16777216);       //  8 MB [1024][4096]
    bf16*  hb     = (bf16*)(ws + 25165824);       //  8 MB LN out; dead after qkv GEMM
    bf16*  vt     = (bf16*)(ws + 25165824);       //  8 MB V^T (aliases hb; reused for LN2)
    bf16*  qkv    = (bf16*)(ws + 33554432);       // 24 MB [4096][3072]
    bf16*  yb     = (bf16*)(ws + 58720256);       //  8 MB attn out [4096][1024]
    float* x1     = (float*)(ws + 67108864);      // 16 MB residual fp32
    bf16*  h3     = (bf16*)(ws + 33554432);       // 32 MB gelu out (aliases dead qkv+yb)

    const dim3 tb(32, 8);
    prep_kernel<<<dim3(16384), dim3(256), 0, stream>>>(Wqkv, Wproj, Wfc1, Wfc2,
                                                       Wqkvt, Wprojt, Wfc1t, Wfc2t,
                                                       x, ln1g, ln1b, hb);
    gemm256<0><<<dim3(12, 16), dim3(512), 0, stream>>>(hb, Wqkvt, qkv, 4096, 3072, 1024);
    transpose_v<<<dim3(64, 2, 32), tb, 0, stream>>>(qkv, vt);
    attn_kernel<<<dim3(16, 16, 2), dim3(256), 0, stream>>>(qkv, vt, yb);
    gemm128p<<<dim3(8, 32), dim3(512), 0, stream>>>(yb, Wprojt, x, x1, 4096, 1024, 1024);
    ln_kernel<<<dim3(4096), dim3(256), 0, stream>>>(x1, ln2g, ln2b, hb);
    gemm256<2><<<dim3(16, 16), dim3(512), 0, stream>>>(hb, Wfc1t, h3, 4096, 4096, 1024);
    gemm128p<<<dim3(8, 32), dim3(512), 0, stream>>>(h3, Wfc2t, x1, out, 4096, 1024, 4096);
}